// Round 8
// baseline (467.072 us; speedup 1.0000x reference)
//
#include <hip/hip_runtime.h>

#define NN 100000
#define NE 1600000
#define HID 128
#define NG 512
#define MAXZ 1000
#define NBK 256           // dst-range buckets
#define BK_S 391          // nodes per bucket (256*391 = 100096 >= NN)
#define TILE_E 4096       // edges per scatter tile (16/thread)

typedef unsigned short u16;
typedef unsigned int u32;
typedef __attribute__((ext_vector_type(8))) short bf16x8;
typedef __attribute__((ext_vector_type(4))) float f32x4;

__device__ __forceinline__ u16 bf16r(float x) {     // RNE f32->bf16
    u32 u = __float_as_uint(x);
    u32 r = (u + 0x7fffu + ((u >> 16) & 1u)) >> 16;
    return (u16)r;
}
__device__ __forceinline__ float bflo(u32 u) { return __uint_as_float(u << 16); }
__device__ __forceinline__ float bfhi(u32 u) { return __uint_as_float(u & 0xffff0000u); }

// ---------------- CSR build ----------------
__global__ __launch_bounds__(256) void bucket_count_kernel(const int* __restrict__ dst,
                                                           int* __restrict__ bcount) {
    __shared__ int lh[NBK];
    int t = threadIdx.x;
    lh[t] = 0;
    __syncthreads();
    int stride = gridDim.x * 256;
    for (int i = blockIdx.x * 256 + t; i < NE; i += stride)
        atomicAdd(&lh[dst[i] / BK_S], 1);
    __syncthreads();
    int v = lh[t];
    if (v) atomicAdd(&bcount[t], v);
}

__global__ __launch_bounds__(NBK) void scan_nbk_kernel(const int* __restrict__ bcount,
                                                       int* __restrict__ boff,
                                                       int* __restrict__ gcursor) {
    __shared__ int buf[NBK];
    int t = threadIdx.x;
    int v = bcount[t];
    buf[t] = v;
    __syncthreads();
    for (int d = 1; d < NBK; d <<= 1) {
        int add = (t >= d) ? buf[t - d] : 0;
        __syncthreads();
        buf[t] += add;
        __syncthreads();
    }
    int excl = buf[t] - v;
    boff[t] = excl;
    gcursor[t] = excl;
    if (t == NBK - 1) boff[NBK] = buf[NBK - 1];
}

__global__ __launch_bounds__(256) void pair_scatter_kernel(const int* __restrict__ src,
                                                           const int* __restrict__ dst,
                                                           int* __restrict__ gcursor,
                                                           u32* __restrict__ pairs) {
    __shared__ int cnt[NBK];
    __shared__ int base[NBK];
    int t = threadIdx.x;
    long tile0 = (long)blockIdx.x * TILE_E;
    cnt[t] = 0;
    __syncthreads();
    u32 val[16], br[16];
#pragma unroll
    for (int i = 0; i < 16; ++i) {
        long idx = tile0 + i * 256 + t;
        val[i] = 0xFFFFFFFFu;
        if (idx < NE) {
            int d = dst[idx];
            int b = d / BK_S;
            int r = atomicAdd(&cnt[b], 1);
            val[i] = ((u32)(d - b * BK_S) << 17) | (u32)src[idx];
            br[i] = ((u32)b << 12) | (u32)r;
        }
    }
    __syncthreads();
    int c = cnt[t];
    if (c) base[t] = atomicAdd(&gcursor[t], c);
    __syncthreads();
#pragma unroll
    for (int i = 0; i < 16; ++i) {
        if (val[i] != 0xFFFFFFFFu) {
            u32 b = br[i] >> 12, r = br[i] & 0xFFFu;
            pairs[base[b] + r] = val[i];
        }
    }
}

__global__ __launch_bounds__(256) void bucket_build_kernel(const u32* __restrict__ pairs,
                                                           const int* __restrict__ boff,
                                                           int* __restrict__ off,
                                                           int* __restrict__ csr) {
    __shared__ int lh[BK_S];
    __shared__ int ts[256];
    int b = blockIdx.x, t = threadIdx.x;
    int base = boff[b], end = boff[b + 1];
    int node0 = b * BK_S;
    for (int i = t; i < BK_S; i += 256) lh[i] = 0;
    __syncthreads();
    for (int j = base + t; j < end; j += 256)
        atomicAdd(&lh[pairs[j] >> 17], 1);
    __syncthreads();
    int i0 = t * 2, i1 = t * 2 + 1;
    int c0 = (i0 < BK_S) ? lh[i0] : 0;
    int c1 = (i1 < BK_S) ? lh[i1] : 0;
    int s = c0 + c1;
    ts[t] = s;
    __syncthreads();
    for (int d = 1; d < 256; d <<= 1) {
        int add = (t >= d) ? ts[t - d] : 0;
        __syncthreads();
        ts[t] += add;
        __syncthreads();
    }
    int e0 = base + ts[t] - s;
    int e1 = e0 + c0;
    if (i0 < BK_S) { lh[i0] = e0; int n = node0 + i0; if (n < NN) off[n] = e0; }
    if (i1 < BK_S) { lh[i1] = e1; int n = node0 + i1; if (n < NN) off[n] = e1; }
    if (b == 0 && t == 0) off[NN] = NE;
    __syncthreads();
    for (int j = base + t; j < end; j += 256) {
        u32 p = pairs[j];
        int pos = atomicAdd(&lh[p >> 17], 1);
        csr[pos] = (int)(p & 0x1FFFFu);
    }
}

// ---------------- weight transpose+convert: Wt[n][k] = bf16(W[k][n]) ----------------
__global__ __launch_bounds__(128) void wt_kernel(const float* __restrict__ W, u16* __restrict__ Wt) {
    int k = blockIdx.x, n = threadIdx.x;
    Wt[n * HID + k] = bf16r(W[k * HID + n]);
}

// ---------------- f32 VALU GEMM (only for tiny zW table) ----------------
#define FMA4(acc, s, w) { acc.x += (s)*(w).x; acc.y += (s)*(w).y; acc.z += (s)*(w).z; acc.w += (s)*(w).w; }
__global__ __launch_bounds__(256) void gemm128_kernel(
    const float* __restrict__ X, const float* __restrict__ W,
    float* __restrict__ Y, int nrows)
{
    __shared__ float xs[32][132];
    int t = threadIdx.x;
    int row0 = blockIdx.x * 32;
    int sr = t >> 5;
    int sk = (t & 31) * 4;
#pragma unroll
    for (int p = 0; p < 4; ++p) {
        int r = p * 8 + sr;
        int grow = row0 + r;
        float4 v = make_float4(0.f, 0.f, 0.f, 0.f);
        if (grow < nrows) v = *(const float4*)(X + (long)grow * HID + sk);
        *(float4*)(&xs[r][sk]) = v;
    }
    __syncthreads();
    int cg = t & 31, rg = t >> 5;
    int c = cg * 4, r = rg * 4;
    float4 a0 = make_float4(0,0,0,0), a1 = a0, a2 = a0, a3 = a0;
    for (int k = 0; k < 128; k += 4) {
        float x0[4], x1[4], x2[4], x3[4];
        *(float4*)x0 = *(const float4*)&xs[r + 0][k];
        *(float4*)x1 = *(const float4*)&xs[r + 1][k];
        *(float4*)x2 = *(const float4*)&xs[r + 2][k];
        *(float4*)x3 = *(const float4*)&xs[r + 3][k];
#pragma unroll
        for (int j = 0; j < 4; ++j) {
            float4 w = *(const float4*)(W + (k + j) * HID + c);
            FMA4(a0, x0[j], w); FMA4(a1, x1[j], w); FMA4(a2, x2[j], w); FMA4(a3, x3[j], w);
        }
    }
    float4 accs[4] = {a0, a1, a2, a3};
#pragma unroll
    for (int i = 0; i < 4; ++i) {
        int grow = row0 + r + i;
        if (grow < nrows) *(float4*)(Y + (long)grow * HID + c) = accs[i];
    }
}

// ---------------- MFMA core: A in LDS, W fragments straight from L2 ----------------
__device__ __forceinline__ void mfma_phase(const u16 (*Als)[136], const u16* __restrict__ Wt,
                                           const float* __restrict__ addTab, const int* __restrict__ addIdx,
                                           u16* __restrict__ Y, int row0, int nrows, int t)
{
    int w = t >> 6, l = t & 63;
    int lr = l & 15, lq = l >> 4;
    f32x4 acc[8];
#pragma unroll
    for (int i = 0; i < 8; ++i) acc[i] = (f32x4){0.f, 0.f, 0.f, 0.f};

#pragma unroll
    for (int kk = 0; kk < 4; ++kk) {
        bf16x8 af = *(const bf16x8*)&Als[w * 16 + lr][kk * 32 + lq * 8];
#pragma unroll
        for (int nt = 0; nt < 8; ++nt) {
            bf16x8 bf = *(const bf16x8*)(Wt + (nt * 16 + lr) * HID + kk * 32 + lq * 8);
            acc[nt] = __builtin_amdgcn_mfma_f32_16x16x32_bf16(af, bf, acc[nt], 0, 0, 0);
        }
    }

    int orow = row0 + w * 16 + lq * 4;
#pragma unroll
    for (int r = 0; r < 4; ++r) {
        int grow = orow + r;
        if (grow < nrows) {
            const float* ap = addTab ? (addTab + (long)addIdx[grow] * HID) : nullptr;
#pragma unroll
            for (int nt = 0; nt < 8; ++nt) {
                int col = nt * 16 + lr;
                float v = acc[nt][r];
                if (ap) v += ap[col];
                Y[(long)grow * HID + col] = bf16r(v);
            }
        }
    }
}

// ---------------- layer-0 GEMM: Y = bf16(node_emb[nid]) @ Wt + zW[z] ----------------
__global__ __launch_bounds__(256) void gemm0_kernel(
    const float* __restrict__ X, const int* __restrict__ gatherIdx,
    const u16* __restrict__ Wt,
    const float* __restrict__ addTab, const int* __restrict__ addIdx,
    u16* __restrict__ Y, int nrows)
{
    __shared__ u16 Als[64][136];
    int t = threadIdx.x;
    int row0 = blockIdx.x * 64;
#pragma unroll
    for (int p = 0; p < 8; ++p) {
        int r = p * 8 + (t >> 5);
        int k0 = (t & 31) * 4;
        int grow = row0 + r;
        float4 v = make_float4(0.f, 0.f, 0.f, 0.f);
        if (grow < nrows) {
            long srow = (long)gatherIdx[grow];
            v = *(const float4*)(X + srow * HID + k0);
        }
        ushort4 b;
        b.x = bf16r(v.x); b.y = bf16r(v.y); b.z = bf16r(v.z); b.w = bf16r(v.w);
        *(ushort4*)&Als[r][k0] = b;
    }
    __syncthreads();
    mfma_phase(Als, Wt, addTab, addIdx, Y, row0, nrows, t);
}

// ---------------- fused aggregate(+bias+relu) -> GEMM ----------------
// Block = 256 thr, 64 nodes. Phase 1: wave w aggregates rows w*16..w*16+15 into
// LDS (gather identical to aggregate_kernel). Phase 2: MFMA, W from L2.
__global__ __launch_bounds__(256) void fused_agg_gemm_kernel(
    const u16* __restrict__ H,
    const int* __restrict__ off, const int* __restrict__ csr,
    const float* __restrict__ bias,
    const u16* __restrict__ Wt, u16* __restrict__ Y)
{
    __shared__ u16 Als[64][136];
    int t = threadIdx.x;
    int row0 = blockIdx.x * 64;
    int w = t >> 6, l = t & 63;
    int g = l >> 4, fl = l & 15;

    for (int i = 0; i < 16; ++i) {
        int r = w * 16 + i;
        int node = row0 + r;
        float acc[8] = {0.f, 0.f, 0.f, 0.f, 0.f, 0.f, 0.f, 0.f};
        if (node < NN) {
            int s = off[node], e = off[node + 1];
            int j = s + g;
            for (; j + 4 < e; j += 8) {
                int i0 = csr[j];
                int i1 = csr[j + 4];
                uint4 v0 = *(const uint4*)(H + (long)i0 * HID + fl * 8);
                uint4 v1 = *(const uint4*)(H + (long)i1 * HID + fl * 8);
                acc[0] += bflo(v0.x); acc[1] += bfhi(v0.x);
                acc[2] += bflo(v0.y); acc[3] += bfhi(v0.y);
                acc[4] += bflo(v0.z); acc[5] += bfhi(v0.z);
                acc[6] += bflo(v0.w); acc[7] += bfhi(v0.w);
                acc[0] += bflo(v1.x); acc[1] += bfhi(v1.x);
                acc[2] += bflo(v1.y); acc[3] += bfhi(v1.y);
                acc[4] += bflo(v1.z); acc[5] += bfhi(v1.z);
                acc[6] += bflo(v1.w); acc[7] += bfhi(v1.w);
            }
            if (j < e) {
                int i0 = csr[j];
                uint4 v0 = *(const uint4*)(H + (long)i0 * HID + fl * 8);
                acc[0] += bflo(v0.x); acc[1] += bfhi(v0.x);
                acc[2] += bflo(v0.y); acc[3] += bfhi(v0.y);
                acc[4] += bflo(v0.z); acc[5] += bfhi(v0.z);
                acc[6] += bflo(v0.w); acc[7] += bfhi(v0.w);
            }
#pragma unroll
            for (int q = 0; q < 8; ++q) {
                acc[q] += __shfl_xor(acc[q], 16);
                acc[q] += __shfl_xor(acc[q], 32);
            }
            if (g == 0) {
                uint4 sv = *(const uint4*)(H + (long)node * HID + fl * 8);
                float4 ba = *(const float4*)(bias + fl * 8);
                float4 bb = *(const float4*)(bias + fl * 8 + 4);
                float rr[8];
                rr[0] = acc[0] + bflo(sv.x) + ba.x;
                rr[1] = acc[1] + bfhi(sv.x) + ba.y;
                rr[2] = acc[2] + bflo(sv.y) + ba.z;
                rr[3] = acc[3] + bfhi(sv.y) + ba.w;
                rr[4] = acc[4] + bflo(sv.z) + bb.x;
                rr[5] = acc[5] + bfhi(sv.z) + bb.y;
                rr[6] = acc[6] + bflo(sv.w) + bb.z;
                rr[7] = acc[7] + bfhi(sv.w) + bb.w;
                uint4 ov;
                ov.x = (u32)bf16r(fmaxf(rr[0], 0.f)) | ((u32)bf16r(fmaxf(rr[1], 0.f)) << 16);
                ov.y = (u32)bf16r(fmaxf(rr[2], 0.f)) | ((u32)bf16r(fmaxf(rr[3], 0.f)) << 16);
                ov.z = (u32)bf16r(fmaxf(rr[4], 0.f)) | ((u32)bf16r(fmaxf(rr[5], 0.f)) << 16);
                ov.w = (u32)bf16r(fmaxf(rr[6], 0.f)) | ((u32)bf16r(fmaxf(rr[7], 0.f)) << 16);
                *(uint4*)&Als[r][fl * 8] = ov;
            }
        } else if (g == 0) {
            uint4 z4 = make_uint4(0, 0, 0, 0);
            *(uint4*)&Als[r][fl * 8] = z4;
        }
    }
    __syncthreads();
    mfma_phase(Als, Wt, nullptr, nullptr, Y, row0, NN, t);
}

// ---------------- aggregate (bf16 H), standalone (final layer, no relu) ----------------
__global__ __launch_bounds__(256) void aggregate_kernel(
    const u16* __restrict__ H, u16* __restrict__ Xo,
    const int* __restrict__ off, const int* __restrict__ csr,
    const float* __restrict__ bias, int n, int doRelu)
{
    int node = blockIdx.x * 4 + (threadIdx.x >> 6);
    if (node >= n) return;
    int lane = threadIdx.x & 63;
    int g = lane >> 4, fl = lane & 15;
    int s = off[node], e = off[node + 1];

    float acc[8] = {0.f, 0.f, 0.f, 0.f, 0.f, 0.f, 0.f, 0.f};
    int j = s + g;

    for (; j + 4 < e; j += 8) {
        int i0 = csr[j];
        int i1 = csr[j + 4];
        uint4 v0 = *(const uint4*)(H + (long)i0 * HID + fl * 8);
        uint4 v1 = *(const uint4*)(H + (long)i1 * HID + fl * 8);
        acc[0] += bflo(v0.x); acc[1] += bfhi(v0.x);
        acc[2] += bflo(v0.y); acc[3] += bfhi(v0.y);
        acc[4] += bflo(v0.z); acc[5] += bfhi(v0.z);
        acc[6] += bflo(v0.w); acc[7] += bfhi(v0.w);
        acc[0] += bflo(v1.x); acc[1] += bfhi(v1.x);
        acc[2] += bflo(v1.y); acc[3] += bfhi(v1.y);
        acc[4] += bflo(v1.z); acc[5] += bfhi(v1.z);
        acc[6] += bflo(v1.w); acc[7] += bfhi(v1.w);
    }
    if (j < e) {
        int i0 = csr[j];
        uint4 v0 = *(const uint4*)(H + (long)i0 * HID + fl * 8);
        acc[0] += bflo(v0.x); acc[1] += bfhi(v0.x);
        acc[2] += bflo(v0.y); acc[3] += bfhi(v0.y);
        acc[4] += bflo(v0.z); acc[5] += bfhi(v0.z);
        acc[6] += bflo(v0.w); acc[7] += bfhi(v0.w);
    }

#pragma unroll
    for (int i = 0; i < 8; ++i) {
        acc[i] += __shfl_xor(acc[i], 16);
        acc[i] += __shfl_xor(acc[i], 32);
    }

    if (g == 0) {
        uint4 sv = *(const uint4*)(H + (long)node * HID + fl * 8);
        float4 ba = *(const float4*)(bias + fl * 8);
        float4 bb = *(const float4*)(bias + fl * 8 + 4);
        float r[8];
        r[0] = acc[0] + bflo(sv.x) + ba.x;
        r[1] = acc[1] + bfhi(sv.x) + ba.y;
        r[2] = acc[2] + bflo(sv.y) + ba.z;
        r[3] = acc[3] + bfhi(sv.y) + ba.w;
        r[4] = acc[4] + bflo(sv.z) + bb.x;
        r[5] = acc[5] + bfhi(sv.z) + bb.y;
        r[6] = acc[6] + bflo(sv.w) + bb.z;
        r[7] = acc[7] + bfhi(sv.w) + bb.w;
        if (doRelu) {
#pragma unroll
            for (int i = 0; i < 8; ++i) r[i] = fmaxf(r[i], 0.f);
        }
        uint4 ov;
        ov.x = (u32)bf16r(r[0]) | ((u32)bf16r(r[1]) << 16);
        ov.y = (u32)bf16r(r[2]) | ((u32)bf16r(r[3]) << 16);
        ov.z = (u32)bf16r(r[4]) | ((u32)bf16r(r[5]) << 16);
        ov.w = (u32)bf16r(r[6]) | ((u32)bf16r(r[7]) << 16);
        *(uint4*)(Xo + (long)node * HID + fl * 8) = ov;
    }
}

// ---------------- pooling: per-graph mean, coalesced uint4 rows ----------------
__global__ __launch_bounds__(256) void pool_kernel(const u16* __restrict__ X, const int* __restrict__ batch,
                                                   int n, float* __restrict__ pooled) {
    __shared__ float red[4][HID];
    int g = blockIdx.x;
    int t = threadIdx.x;
    int grp = t >> 4, fl = t & 15;
    int lo = 0, hi = n;
    while (lo < hi) { int m = (lo + hi) >> 1; if (batch[m] < g) lo = m + 1; else hi = m; }
    int s = lo;
    lo = 0; hi = n;
    while (lo < hi) { int m = (lo + hi) >> 1; if (batch[m] < g + 1) lo = m + 1; else hi = m; }
    int e = lo;

    float acc[8] = {0.f, 0.f, 0.f, 0.f, 0.f, 0.f, 0.f, 0.f};
    for (int i = s + grp; i < e; i += 16) {
        uint4 v = *(const uint4*)(X + (long)i * HID + fl * 8);
        acc[0] += bflo(v.x); acc[1] += bfhi(v.x);
        acc[2] += bflo(v.y); acc[3] += bfhi(v.y);
        acc[4] += bflo(v.z); acc[5] += bfhi(v.z);
        acc[6] += bflo(v.w); acc[7] += bfhi(v.w);
    }
#pragma unroll
    for (int i = 0; i < 8; ++i) {
        acc[i] += __shfl_xor(acc[i], 16);
        acc[i] += __shfl_xor(acc[i], 32);
    }
    int w = t >> 6, lane = t & 63;
    if (lane < 16) {
#pragma unroll
        for (int i = 0; i < 8; ++i) red[w][lane * 8 + i] = acc[i];
    }
    __syncthreads();
    if (t < HID) {
        float v = red[0][t] + red[1][t] + red[2][t] + red[3][t];
        float cnt = (float)(e - s);
        pooled[g * HID + t] = v / fmaxf(cnt, 1.f);
    }
}

// ---------------- MLP head ----------------
__global__ __launch_bounds__(128) void mlp_kernel(
    const float* __restrict__ pooled, const float* __restrict__ W1, const float* __restrict__ b1,
    const float* __restrict__ gamma, const float* __restrict__ beta,
    const float* __restrict__ W2, const float* __restrict__ b2, float* __restrict__ out)
{
    int g = blockIdx.x, t = threadIdx.x;
    __shared__ float p[HID];
    __shared__ float red[4];
    p[t] = pooled[g * HID + t];
    __syncthreads();
    float acc = b1[t];
    for (int k = 0; k < HID; ++k) acc += p[k] * W1[k * HID + t];
    const float inv = 1.0f / sqrtf(1.0f + 1e-5f);
    acc = acc * (gamma[t] * inv) + beta[t];
    acc = fmaxf(acc, 0.f);
    float v0 = acc * W2[t * 2 + 0];
    float v1 = acc * W2[t * 2 + 1];
    for (int d = 32; d > 0; d >>= 1) { v0 += __shfl_down(v0, d); v1 += __shfl_down(v1, d); }
    int w = t >> 6, lane = t & 63;
    if (lane == 0) { red[w * 2] = v0; red[w * 2 + 1] = v1; }
    __syncthreads();
    if (t == 0) {
        out[g * 2 + 0] = red[0] + red[2] + b2[0];
        out[g * 2 + 1] = red[1] + red[3] + b2[1];
    }
}

extern "C" void kernel_launch(void* const* d_in, const int* in_sizes, int n_in,
                              void* d_out, int out_size, void* d_ws, size_t ws_size,
                              hipStream_t stream) {
    const int*   z        = (const int*)d_in[1];
    const int*   ei       = (const int*)d_in[2];
    const int*   batch    = (const int*)d_in[3];
    const int*   node_id  = (const int*)d_in[4];
    const float* z_emb    = (const float*)d_in[5];
    const float* node_emb = (const float*)d_in[6];
    const float* W0  = (const float*)d_in[7];
    const float* b0  = (const float*)d_in[8];
    const float* W1  = (const float*)d_in[9];
    const float* b1  = (const float*)d_in[10];
    const float* W2  = (const float*)d_in[11];
    const float* b2  = (const float*)d_in[12];
    const float* mW1 = (const float*)d_in[13];
    const float* mb1 = (const float*)d_in[14];
    const float* gam = (const float*)d_in[15];
    const float* bet = (const float*)d_in[16];
    const float* mW2 = (const float*)d_in[17];
    const float* mb2 = (const float*)d_in[18];
    float* out = (float*)d_out;

    const int* srcArr = ei;
    const int* dstArr = ei + NE;

    char* ws = (char*)d_ws;
    size_t o = 0;
    auto alloc = [&](size_t bytes) { char* p = ws + o; o += (bytes + 255) & ~(size_t)255; return p; };
    u16*   A      = (u16*)alloc((size_t)NN * HID * 2);
    u16*   B      = (u16*)alloc((size_t)NN * HID * 2);
    float* zW     = (float*)alloc((size_t)MAXZ * HID * 4);
    u16*   W0bt   = (u16*)alloc((size_t)HID * HID * 2);
    u16*   W1t    = (u16*)alloc((size_t)HID * HID * 2);
    u16*   W2t    = (u16*)alloc((size_t)HID * HID * 2);
    int*   bcount = (int*)alloc((size_t)NBK * 4);
    int*   boff   = (int*)alloc((size_t)(NBK + 1) * 4);
    int*   gcur   = (int*)alloc((size_t)NBK * 4);
    u32*   pairs  = (u32*)alloc((size_t)NE * 4);
    int*   off    = (int*)alloc((size_t)(NN + 1) * 4);
    int*   csr    = (int*)alloc((size_t)NE * 4);
    float* pooled = (float*)alloc((size_t)NG * HID * 4);
    (void)ws_size;

    // CSR by dst — staged bucketed build
    hipMemsetAsync(bcount, 0, (size_t)NBK * 4, stream);
    bucket_count_kernel<<<256, 256, 0, stream>>>(dstArr, bcount);
    scan_nbk_kernel<<<1, NBK, 0, stream>>>(bcount, boff, gcur);
    pair_scatter_kernel<<<(NE + TILE_E - 1) / TILE_E, 256, 0, stream>>>(srcArr, dstArr, gcur, pairs);
    bucket_build_kernel<<<NBK, 256, 0, stream>>>(pairs, boff, off, csr);

    // weights
    wt_kernel<<<HID, HID, 0, stream>>>(W0 + HID * HID, W0bt);
    wt_kernel<<<HID, HID, 0, stream>>>(W1, W1t);
    wt_kernel<<<HID, HID, 0, stream>>>(W2, W2t);

    // zW = z_emb @ W0_top   (f32, tiny)
    gemm128_kernel<<<(MAXZ + 31) / 32, 256, 0, stream>>>(z_emb, W0, zW, MAXZ);

    const int GB = (NN + 63) / 64;
    // layer 0: B = bf16( node_emb[node_id] @ W0_bot + zW[z] )
    gemm0_kernel<<<GB, 256, 0, stream>>>(node_emb, node_id, W0bt, zW, z, B, NN);
    // layers 1,2: fused aggregate(+b+relu) -> GEMM
    fused_agg_gemm_kernel<<<GB, 256, 0, stream>>>(B, off, csr, b0, W1t, A);
    fused_agg_gemm_kernel<<<GB, 256, 0, stream>>>(A, off, csr, b1, W2t, B);
    // final aggregate (no relu)
    aggregate_kernel<<<NN / 4, 256, 0, stream>>>(B, A, off, csr, b2, NN, 0);

    pool_kernel<<<NG, 256, 0, stream>>>(A, batch, NN, pooled);
    mlp_kernel<<<NG, 128, 0, stream>>>(pooled, mW1, mb1, gam, bet, mW2, mb2, out);
}

// Round 9
// 424.331 us; speedup vs baseline: 1.1007x; 1.1007x over previous
//
#include <hip/hip_runtime.h>

#define NN 100000
#define NE 1600000
#define HID 128
#define NG 512
#define MAXZ 1000
#define NBK 256           // dst-range buckets
#define BK_S 391          // nodes per bucket (256*391 = 100096 >= NN)
#define TILE_E 4096       // edges per scatter tile (16/thread)

typedef unsigned short u16;
typedef unsigned int u32;
typedef __attribute__((ext_vector_type(8))) short bf16x8;
typedef __attribute__((ext_vector_type(4))) float f32x4;

__device__ __forceinline__ u16 bf16r(float x) {     // RNE f32->bf16
    u32 u = __float_as_uint(x);
    u32 r = (u + 0x7fffu + ((u >> 16) & 1u)) >> 16;
    return (u16)r;
}
__device__ __forceinline__ float bflo(u32 u) { return __uint_as_float(u << 16); }
__device__ __forceinline__ float bfhi(u32 u) { return __uint_as_float(u & 0xffff0000u); }

#define ACC8(v) { \
    acc[0] += bflo((v).x); acc[1] += bfhi((v).x); \
    acc[2] += bflo((v).y); acc[3] += bfhi((v).y); \
    acc[4] += bflo((v).z); acc[5] += bfhi((v).z); \
    acc[6] += bflo((v).w); acc[7] += bfhi((v).w); }

// ---------------- CSR build ----------------
__global__ __launch_bounds__(256) void bucket_count_kernel(const int* __restrict__ dst,
                                                           int* __restrict__ bcount) {
    __shared__ int lh[NBK];
    int t = threadIdx.x;
    lh[t] = 0;
    __syncthreads();
    int stride = gridDim.x * 256;
    for (int i = blockIdx.x * 256 + t; i < NE; i += stride)
        atomicAdd(&lh[dst[i] / BK_S], 1);
    __syncthreads();
    int v = lh[t];
    if (v) atomicAdd(&bcount[t], v);
}

__global__ __launch_bounds__(NBK) void scan_nbk_kernel(const int* __restrict__ bcount,
                                                       int* __restrict__ boff,
                                                       int* __restrict__ gcursor) {
    __shared__ int buf[NBK];
    int t = threadIdx.x;
    int v = bcount[t];
    buf[t] = v;
    __syncthreads();
    for (int d = 1; d < NBK; d <<= 1) {
        int add = (t >= d) ? buf[t - d] : 0;
        __syncthreads();
        buf[t] += add;
        __syncthreads();
    }
    int excl = buf[t] - v;
    boff[t] = excl;
    gcursor[t] = excl;
    if (t == NBK - 1) boff[NBK] = buf[NBK - 1];
}

__global__ __launch_bounds__(256) void pair_scatter_kernel(const int* __restrict__ src,
                                                           const int* __restrict__ dst,
                                                           int* __restrict__ gcursor,
                                                           u32* __restrict__ pairs) {
    __shared__ int cnt[NBK];
    __shared__ int base[NBK];
    int t = threadIdx.x;
    long tile0 = (long)blockIdx.x * TILE_E;
    cnt[t] = 0;
    __syncthreads();
    u32 val[16], br[16];
#pragma unroll
    for (int i = 0; i < 16; ++i) {
        long idx = tile0 + i * 256 + t;
        val[i] = 0xFFFFFFFFu;
        if (idx < NE) {
            int d = dst[idx];
            int b = d / BK_S;
            int r = atomicAdd(&cnt[b], 1);
            val[i] = ((u32)(d - b * BK_S) << 17) | (u32)src[idx];
            br[i] = ((u32)b << 12) | (u32)r;
        }
    }
    __syncthreads();
    int c = cnt[t];
    if (c) base[t] = atomicAdd(&gcursor[t], c);
    __syncthreads();
#pragma unroll
    for (int i = 0; i < 16; ++i) {
        if (val[i] != 0xFFFFFFFFu) {
            u32 b = br[i] >> 12, r = br[i] & 0xFFFu;
            pairs[base[b] + r] = val[i];
        }
    }
}

__global__ __launch_bounds__(256) void bucket_build_kernel(const u32* __restrict__ pairs,
                                                           const int* __restrict__ boff,
                                                           int* __restrict__ off,
                                                           int* __restrict__ csr) {
    __shared__ int lh[BK_S];
    __shared__ int ts[256];
    int b = blockIdx.x, t = threadIdx.x;
    int base = boff[b], end = boff[b + 1];
    int node0 = b * BK_S;
    for (int i = t; i < BK_S; i += 256) lh[i] = 0;
    __syncthreads();
    for (int j = base + t; j < end; j += 256)
        atomicAdd(&lh[pairs[j] >> 17], 1);
    __syncthreads();
    int i0 = t * 2, i1 = t * 2 + 1;
    int c0 = (i0 < BK_S) ? lh[i0] : 0;
    int c1 = (i1 < BK_S) ? lh[i1] : 0;
    int s = c0 + c1;
    ts[t] = s;
    __syncthreads();
    for (int d = 1; d < 256; d <<= 1) {
        int add = (t >= d) ? ts[t - d] : 0;
        __syncthreads();
        ts[t] += add;
        __syncthreads();
    }
    int e0 = base + ts[t] - s;
    int e1 = e0 + c0;
    if (i0 < BK_S) { lh[i0] = e0; int n = node0 + i0; if (n < NN) off[n] = e0; }
    if (i1 < BK_S) { lh[i1] = e1; int n = node0 + i1; if (n < NN) off[n] = e1; }
    if (b == 0 && t == 0) off[NN] = NE;
    __syncthreads();
    for (int j = base + t; j < end; j += 256) {
        u32 p = pairs[j];
        int pos = atomicAdd(&lh[p >> 17], 1);
        csr[pos] = (int)(p & 0x1FFFFu);
    }
}

// ---------------- weight transpose+convert: Wt[n][k] = bf16(W[k][n]) ----------------
__global__ __launch_bounds__(128) void wt_kernel(const float* __restrict__ W, u16* __restrict__ Wt) {
    int k = blockIdx.x, n = threadIdx.x;
    Wt[n * HID + k] = bf16r(W[k * HID + n]);
}

// ---------------- f32 VALU GEMM (only for tiny zW table) ----------------
#define FMA4(acc, s, w) { acc.x += (s)*(w).x; acc.y += (s)*(w).y; acc.z += (s)*(w).z; acc.w += (s)*(w).w; }
__global__ __launch_bounds__(256) void gemm128_kernel(
    const float* __restrict__ X, const float* __restrict__ W,
    float* __restrict__ Y, int nrows)
{
    __shared__ float xs[32][132];
    int t = threadIdx.x;
    int row0 = blockIdx.x * 32;
    int sr = t >> 5;
    int sk = (t & 31) * 4;
#pragma unroll
    for (int p = 0; p < 4; ++p) {
        int r = p * 8 + sr;
        int grow = row0 + r;
        float4 v = make_float4(0.f, 0.f, 0.f, 0.f);
        if (grow < nrows) v = *(const float4*)(X + (long)grow * HID + sk);
        *(float4*)(&xs[r][sk]) = v;
    }
    __syncthreads();
    int cg = t & 31, rg = t >> 5;
    int c = cg * 4, r = rg * 4;
    float4 a0 = make_float4(0,0,0,0), a1 = a0, a2 = a0, a3 = a0;
    for (int k = 0; k < 128; k += 4) {
        float x0[4], x1[4], x2[4], x3[4];
        *(float4*)x0 = *(const float4*)&xs[r + 0][k];
        *(float4*)x1 = *(const float4*)&xs[r + 1][k];
        *(float4*)x2 = *(const float4*)&xs[r + 2][k];
        *(float4*)x3 = *(const float4*)&xs[r + 3][k];
#pragma unroll
        for (int j = 0; j < 4; ++j) {
            float4 w = *(const float4*)(W + (k + j) * HID + c);
            FMA4(a0, x0[j], w); FMA4(a1, x1[j], w); FMA4(a2, x2[j], w); FMA4(a3, x3[j], w);
        }
    }
    float4 accs[4] = {a0, a1, a2, a3};
#pragma unroll
    for (int i = 0; i < 4; ++i) {
        int grow = row0 + r + i;
        if (grow < nrows) *(float4*)(Y + (long)grow * HID + c) = accs[i];
    }
}

// ---------------- MFMA core: A in LDS, W fragments straight from L2 ----------------
__device__ __forceinline__ void mfma_phase(const u16 (*Als)[136], const u16* __restrict__ Wt,
                                           const float* __restrict__ addTab, const int* __restrict__ addIdx,
                                           u16* __restrict__ Y, int row0, int nrows, int t)
{
    int w = t >> 6, l = t & 63;
    int lr = l & 15, lq = l >> 4;
    f32x4 acc[8];
#pragma unroll
    for (int i = 0; i < 8; ++i) acc[i] = (f32x4){0.f, 0.f, 0.f, 0.f};

#pragma unroll
    for (int kk = 0; kk < 4; ++kk) {
        bf16x8 af = *(const bf16x8*)&Als[w * 16 + lr][kk * 32 + lq * 8];
#pragma unroll
        for (int nt = 0; nt < 8; ++nt) {
            bf16x8 bf = *(const bf16x8*)(Wt + (nt * 16 + lr) * HID + kk * 32 + lq * 8);
            acc[nt] = __builtin_amdgcn_mfma_f32_16x16x32_bf16(af, bf, acc[nt], 0, 0, 0);
        }
    }

    int orow = row0 + w * 16 + lq * 4;
#pragma unroll
    for (int r = 0; r < 4; ++r) {
        int grow = orow + r;
        if (grow < nrows) {
            const float* ap = addTab ? (addTab + (long)addIdx[grow] * HID) : nullptr;
#pragma unroll
            for (int nt = 0; nt < 8; ++nt) {
                int col = nt * 16 + lr;
                float v = acc[nt][r];
                if (ap) v += ap[col];
                Y[(long)grow * HID + col] = bf16r(v);
            }
        }
    }
}

// ---------------- MFMA bf16 GEMM: Y = Xsrc @ Wt, A staged in LDS, W from L2 ----------------
template<int SRC_BF16>
__global__ __launch_bounds__(256) void mfma_gemm_kernel(
    const void* __restrict__ Xsrc,
    const int* __restrict__ gatherIdx,
    const u16* __restrict__ Wt,
    const float* __restrict__ addTab, const int* __restrict__ addIdx,
    u16* __restrict__ Y, int nrows)
{
    __shared__ u16 Als[64][136];
    int t = threadIdx.x;
    int row0 = blockIdx.x * 64;

    if (SRC_BF16) {
        const u16* X = (const u16*)Xsrc;
#pragma unroll
        for (int p = 0; p < 4; ++p) {
            int r = p * 16 + (t >> 4);
            int k0 = (t & 15) * 8;
            int grow = row0 + r;
            uint4 v = make_uint4(0, 0, 0, 0);
            if (grow < nrows) {
                long srow = gatherIdx ? (long)gatherIdx[grow] : (long)grow;
                v = *(const uint4*)(X + srow * HID + k0);
            }
            *(uint4*)&Als[r][k0] = v;
        }
    } else {
        const float* X = (const float*)Xsrc;
#pragma unroll
        for (int p = 0; p < 8; ++p) {
            int r = p * 8 + (t >> 5);
            int k0 = (t & 31) * 4;
            int grow = row0 + r;
            float4 v = make_float4(0.f, 0.f, 0.f, 0.f);
            if (grow < nrows) {
                long srow = gatherIdx ? (long)gatherIdx[grow] : (long)grow;
                v = *(const float4*)(X + srow * HID + k0);
            }
            ushort4 b;
            b.x = bf16r(v.x); b.y = bf16r(v.y); b.z = bf16r(v.z); b.w = bf16r(v.w);
            *(ushort4*)&Als[r][k0] = b;
        }
    }
    __syncthreads();
    mfma_phase(Als, Wt, addTab, addIdx, Y, row0, nrows, t);
}

// ---------------- aggregate (bf16 H), 4-deep pipelined gather ----------------
__global__ __launch_bounds__(256) void aggregate_kernel(
    const u16* __restrict__ H, u16* __restrict__ Xo,
    const int* __restrict__ off, const int* __restrict__ csr,
    const float* __restrict__ bias, int n, int doRelu)
{
    int node = blockIdx.x * 4 + (threadIdx.x >> 6);
    if (node >= n) return;
    int lane = threadIdx.x & 63;
    int g = lane >> 4, fl = lane & 15;
    int s = off[node], e = off[node + 1];

    float acc[8] = {0.f, 0.f, 0.f, 0.f, 0.f, 0.f, 0.f, 0.f};
    int j = s + g;

    // 4-deep: edges j, j+4, j+8, j+12 per step (16 outstanding uint4 per wave)
    for (; j + 12 < e; j += 16) {
        int i0 = csr[j];
        int i1 = csr[j + 4];
        int i2 = csr[j + 8];
        int i3 = csr[j + 12];
        uint4 v0 = *(const uint4*)(H + (long)i0 * HID + fl * 8);
        uint4 v1 = *(const uint4*)(H + (long)i1 * HID + fl * 8);
        uint4 v2 = *(const uint4*)(H + (long)i2 * HID + fl * 8);
        uint4 v3 = *(const uint4*)(H + (long)i3 * HID + fl * 8);
        ACC8(v0); ACC8(v1); ACC8(v2); ACC8(v3);
    }
    // 2-deep tail
    for (; j + 4 < e; j += 8) {
        int i0 = csr[j];
        int i1 = csr[j + 4];
        uint4 v0 = *(const uint4*)(H + (long)i0 * HID + fl * 8);
        uint4 v1 = *(const uint4*)(H + (long)i1 * HID + fl * 8);
        ACC8(v0); ACC8(v1);
    }
    if (j < e) {
        int i0 = csr[j];
        uint4 v0 = *(const uint4*)(H + (long)i0 * HID + fl * 8);
        ACC8(v0);
    }

#pragma unroll
    for (int i = 0; i < 8; ++i) {
        acc[i] += __shfl_xor(acc[i], 16);
        acc[i] += __shfl_xor(acc[i], 32);
    }

    if (g == 0) {
        uint4 sv = *(const uint4*)(H + (long)node * HID + fl * 8);
        float4 ba = *(const float4*)(bias + fl * 8);
        float4 bb = *(const float4*)(bias + fl * 8 + 4);
        float r[8];
        r[0] = acc[0] + bflo(sv.x) + ba.x;
        r[1] = acc[1] + bfhi(sv.x) + ba.y;
        r[2] = acc[2] + bflo(sv.y) + ba.z;
        r[3] = acc[3] + bfhi(sv.y) + ba.w;
        r[4] = acc[4] + bflo(sv.z) + bb.x;
        r[5] = acc[5] + bfhi(sv.z) + bb.y;
        r[6] = acc[6] + bflo(sv.w) + bb.z;
        r[7] = acc[7] + bfhi(sv.w) + bb.w;
        if (doRelu) {
#pragma unroll
            for (int i = 0; i < 8; ++i) r[i] = fmaxf(r[i], 0.f);
        }
        uint4 ov;
        ov.x = (u32)bf16r(r[0]) | ((u32)bf16r(r[1]) << 16);
        ov.y = (u32)bf16r(r[2]) | ((u32)bf16r(r[3]) << 16);
        ov.z = (u32)bf16r(r[4]) | ((u32)bf16r(r[5]) << 16);
        ov.w = (u32)bf16r(r[6]) | ((u32)bf16r(r[7]) << 16);
        *(uint4*)(Xo + (long)node * HID + fl * 8) = ov;
    }
}

// ---------------- pooling: per-graph mean, coalesced uint4 rows ----------------
__global__ __launch_bounds__(256) void pool_kernel(const u16* __restrict__ X, const int* __restrict__ batch,
                                                   int n, float* __restrict__ pooled) {
    __shared__ float red[4][HID];
    int g = blockIdx.x;
    int t = threadIdx.x;
    int grp = t >> 4, fl = t & 15;
    int lo = 0, hi = n;
    while (lo < hi) { int m = (lo + hi) >> 1; if (batch[m] < g) lo = m + 1; else hi = m; }
    int s = lo;
    lo = 0; hi = n;
    while (lo < hi) { int m = (lo + hi) >> 1; if (batch[m] < g + 1) lo = m + 1; else hi = m; }
    int e = lo;

    float acc[8] = {0.f, 0.f, 0.f, 0.f, 0.f, 0.f, 0.f, 0.f};
    for (int i = s + grp; i < e; i += 16) {
        uint4 v = *(const uint4*)(X + (long)i * HID + fl * 8);
        ACC8(v);
    }
#pragma unroll
    for (int i = 0; i < 8; ++i) {
        acc[i] += __shfl_xor(acc[i], 16);
        acc[i] += __shfl_xor(acc[i], 32);
    }
    int w = t >> 6, lane = t & 63;
    if (lane < 16) {
#pragma unroll
        for (int i = 0; i < 8; ++i) red[w][lane * 8 + i] = acc[i];
    }
    __syncthreads();
    if (t < HID) {
        float v = red[0][t] + red[1][t] + red[2][t] + red[3][t];
        float cnt = (float)(e - s);
        pooled[g * HID + t] = v / fmaxf(cnt, 1.f);
    }
}

// ---------------- MLP head ----------------
__global__ __launch_bounds__(128) void mlp_kernel(
    const float* __restrict__ pooled, const float* __restrict__ W1, const float* __restrict__ b1,
    const float* __restrict__ gamma, const float* __restrict__ beta,
    const float* __restrict__ W2, const float* __restrict__ b2, float* __restrict__ out)
{
    int g = blockIdx.x, t = threadIdx.x;
    __shared__ float p[HID];
    __shared__ float red[4];
    p[t] = pooled[g * HID + t];
    __syncthreads();
    float acc = b1[t];
    for (int k = 0; k < HID; ++k) acc += p[k] * W1[k * HID + t];
    const float inv = 1.0f / sqrtf(1.0f + 1e-5f);
    acc = acc * (gamma[t] * inv) + beta[t];
    acc = fmaxf(acc, 0.f);
    float v0 = acc * W2[t * 2 + 0];
    float v1 = acc * W2[t * 2 + 1];
    for (int d = 32; d > 0; d >>= 1) { v0 += __shfl_down(v0, d); v1 += __shfl_down(v1, d); }
    int w = t >> 6, lane = t & 63;
    if (lane == 0) { red[w * 2] = v0; red[w * 2 + 1] = v1; }
    __syncthreads();
    if (t == 0) {
        out[g * 2 + 0] = red[0] + red[2] + b2[0];
        out[g * 2 + 1] = red[1] + red[3] + b2[1];
    }
}

extern "C" void kernel_launch(void* const* d_in, const int* in_sizes, int n_in,
                              void* d_out, int out_size, void* d_ws, size_t ws_size,
                              hipStream_t stream) {
    const int*   z        = (const int*)d_in[1];
    const int*   ei       = (const int*)d_in[2];
    const int*   batch    = (const int*)d_in[3];
    const int*   node_id  = (const int*)d_in[4];
    const float* z_emb    = (const float*)d_in[5];
    const float* node_emb = (const float*)d_in[6];
    const float* W0  = (const float*)d_in[7];
    const float* b0  = (const float*)d_in[8];
    const float* W1  = (const float*)d_in[9];
    const float* b1  = (const float*)d_in[10];
    const float* W2  = (const float*)d_in[11];
    const float* b2  = (const float*)d_in[12];
    const float* mW1 = (const float*)d_in[13];
    const float* mb1 = (const float*)d_in[14];
    const float* gam = (const float*)d_in[15];
    const float* bet = (const float*)d_in[16];
    const float* mW2 = (const float*)d_in[17];
    const float* mb2 = (const float*)d_in[18];
    float* out = (float*)d_out;

    const int* srcArr = ei;
    const int* dstArr = ei + NE;

    char* ws = (char*)d_ws;
    size_t o = 0;
    auto alloc = [&](size_t bytes) { char* p = ws + o; o += (bytes + 255) & ~(size_t)255; return p; };
    u16*   A      = (u16*)alloc((size_t)NN * HID * 2);
    u16*   B      = (u16*)alloc((size_t)NN * HID * 2);
    float* zW     = (float*)alloc((size_t)MAXZ * HID * 4);
    u16*   W0bt   = (u16*)alloc((size_t)HID * HID * 2);
    u16*   W1t    = (u16*)alloc((size_t)HID * HID * 2);
    u16*   W2t    = (u16*)alloc((size_t)HID * HID * 2);
    int*   bcount = (int*)alloc((size_t)NBK * 4);
    int*   boff   = (int*)alloc((size_t)(NBK + 1) * 4);
    int*   gcur   = (int*)alloc((size_t)NBK * 4);
    u32*   pairs  = (u32*)alloc((size_t)NE * 4);
    int*   off    = (int*)alloc((size_t)(NN + 1) * 4);
    int*   csr    = (int*)alloc((size_t)NE * 4);
    float* pooled = (float*)alloc((size_t)NG * HID * 4);
    (void)ws_size;

    // CSR by dst — staged bucketed build
    hipMemsetAsync(bcount, 0, (size_t)NBK * 4, stream);
    bucket_count_kernel<<<1024, 256, 0, stream>>>(dstArr, bcount);
    scan_nbk_kernel<<<1, NBK, 0, stream>>>(bcount, boff, gcur);
    pair_scatter_kernel<<<(NE + TILE_E - 1) / TILE_E, 256, 0, stream>>>(srcArr, dstArr, gcur, pairs);
    bucket_build_kernel<<<NBK, 256, 0, stream>>>(pairs, boff, off, csr);

    // weights
    wt_kernel<<<HID, HID, 0, stream>>>(W0 + HID * HID, W0bt);
    wt_kernel<<<HID, HID, 0, stream>>>(W1, W1t);
    wt_kernel<<<HID, HID, 0, stream>>>(W2, W2t);

    // zW = z_emb @ W0_top   (f32, tiny)
    gemm128_kernel<<<(MAXZ + 31) / 32, 256, 0, stream>>>(z_emb, W0, zW, MAXZ);

    const int GB = (NN + 63) / 64;
    // layer 0: B = bf16( node_emb[node_id] @ W0_bot + zW[z] )
    mfma_gemm_kernel<0><<<GB, 256, 0, stream>>>(node_emb, node_id, W0bt, zW, z, B, NN);
    aggregate_kernel<<<NN / 4, 256, 0, stream>>>(B, A, off, csr, b0, NN, 1);
    mfma_gemm_kernel<1><<<GB, 256, 0, stream>>>(A, nullptr, W1t, nullptr, nullptr, B, NN);
    aggregate_kernel<<<NN / 4, 256, 0, stream>>>(B, A, off, csr, b1, NN, 1);
    mfma_gemm_kernel<1><<<GB, 256, 0, stream>>>(A, nullptr, W2t, nullptr, nullptr, B, NN);
    aggregate_kernel<<<NN / 4, 256, 0, stream>>>(B, A, off, csr, b2, NN, 0);

    pool_kernel<<<NG, 256, 0, stream>>>(A, batch, NN, pooled);
    mlp_kernel<<<NG, 128, 0, stream>>>(pooled, mW1, mb1, gam, bet, mW2, mb2, out);
}

// Round 10
// 377.930 us; speedup vs baseline: 1.2359x; 1.1228x over previous
//
#include <hip/hip_runtime.h>

#define NN 100000
#define NE 1600000
#define HID 128
#define NG 512
#define MAXZ 1000
#define NBK 256           // dst-range buckets
#define BK_S 391          // nodes per bucket (256*391 = 100096 >= NN)
#define TILE_E 4096       // edges per scatter tile (16/thread)

typedef unsigned short u16;
typedef unsigned int u32;
typedef __attribute__((ext_vector_type(8))) short bf16x8;
typedef __attribute__((ext_vector_type(4))) float f32x4;

__device__ __forceinline__ u16 bf16r(float x) {     // RNE f32->bf16
    u32 u = __float_as_uint(x);
    u32 r = (u + 0x7fffu + ((u >> 16) & 1u)) >> 16;
    return (u16)r;
}
__device__ __forceinline__ float bflo(u32 u) { return __uint_as_float(u << 16); }
__device__ __forceinline__ float bfhi(u32 u) { return __uint_as_float(u & 0xffff0000u); }

#define ACC8(v) { \
    acc[0] += bflo((v).x); acc[1] += bfhi((v).x); \
    acc[2] += bflo((v).y); acc[3] += bfhi((v).y); \
    acc[4] += bflo((v).z); acc[5] += bfhi((v).z); \
    acc[6] += bflo((v).w); acc[7] += bfhi((v).w); }

// ---------------- CSR build ----------------
__global__ __launch_bounds__(256) void bucket_count_kernel(const int* __restrict__ dst,
                                                           int* __restrict__ bcount) {
    __shared__ int lh[NBK];
    int t = threadIdx.x;
    lh[t] = 0;
    __syncthreads();
    int stride = gridDim.x * 256;
    for (int i = blockIdx.x * 256 + t; i < NE; i += stride)
        atomicAdd(&lh[dst[i] / BK_S], 1);
    __syncthreads();
    int v = lh[t];
    if (v) atomicAdd(&bcount[t], v);
}

__global__ __launch_bounds__(NBK) void scan_nbk_kernel(const int* __restrict__ bcount,
                                                       int* __restrict__ boff,
                                                       int* __restrict__ gcursor) {
    __shared__ int buf[NBK];
    int t = threadIdx.x;
    int v = bcount[t];
    buf[t] = v;
    __syncthreads();
    for (int d = 1; d < NBK; d <<= 1) {
        int add = (t >= d) ? buf[t - d] : 0;
        __syncthreads();
        buf[t] += add;
        __syncthreads();
    }
    int excl = buf[t] - v;
    boff[t] = excl;
    gcursor[t] = excl;
    if (t == NBK - 1) boff[NBK] = buf[NBK - 1];
}

__global__ __launch_bounds__(256) void pair_scatter_kernel(const int* __restrict__ src,
                                                           const int* __restrict__ dst,
                                                           int* __restrict__ gcursor,
                                                           u32* __restrict__ pairs) {
    __shared__ int cnt[NBK];
    __shared__ int base[NBK];
    int t = threadIdx.x;
    long tile0 = (long)blockIdx.x * TILE_E;
    cnt[t] = 0;
    __syncthreads();
    u32 val[16], br[16];
#pragma unroll
    for (int i = 0; i < 16; ++i) {
        long idx = tile0 + i * 256 + t;
        val[i] = 0xFFFFFFFFu;
        if (idx < NE) {
            int d = dst[idx];
            int b = d / BK_S;
            int r = atomicAdd(&cnt[b], 1);
            val[i] = ((u32)(d - b * BK_S) << 17) | (u32)src[idx];
            br[i] = ((u32)b << 12) | (u32)r;
        }
    }
    __syncthreads();
    int c = cnt[t];
    if (c) base[t] = atomicAdd(&gcursor[t], c);
    __syncthreads();
#pragma unroll
    for (int i = 0; i < 16; ++i) {
        if (val[i] != 0xFFFFFFFFu) {
            u32 b = br[i] >> 12, r = br[i] & 0xFFFu;
            pairs[base[b] + r] = val[i];
        }
    }
}

__global__ __launch_bounds__(256) void bucket_build_kernel(const u32* __restrict__ pairs,
                                                           const int* __restrict__ boff,
                                                           int* __restrict__ off,
                                                           int* __restrict__ csr) {
    __shared__ int lh[BK_S];
    __shared__ int ts[256];
    int b = blockIdx.x, t = threadIdx.x;
    int base = boff[b], end = boff[b + 1];
    int node0 = b * BK_S;
    for (int i = t; i < BK_S; i += 256) lh[i] = 0;
    __syncthreads();
    for (int j = base + t; j < end; j += 256)
        atomicAdd(&lh[pairs[j] >> 17], 1);
    __syncthreads();
    int i0 = t * 2, i1 = t * 2 + 1;
    int c0 = (i0 < BK_S) ? lh[i0] : 0;
    int c1 = (i1 < BK_S) ? lh[i1] : 0;
    int s = c0 + c1;
    ts[t] = s;
    __syncthreads();
    for (int d = 1; d < 256; d <<= 1) {
        int add = (t >= d) ? ts[t - d] : 0;
        __syncthreads();
        ts[t] += add;
        __syncthreads();
    }
    int e0 = base + ts[t] - s;
    int e1 = e0 + c0;
    if (i0 < BK_S) { lh[i0] = e0; int n = node0 + i0; if (n < NN) off[n] = e0; }
    if (i1 < BK_S) { lh[i1] = e1; int n = node0 + i1; if (n < NN) off[n] = e1; }
    if (b == 0 && t == 0) off[NN] = NE;
    __syncthreads();
    for (int j = base + t; j < end; j += 256) {
        u32 p = pairs[j];
        int pos = atomicAdd(&lh[p >> 17], 1);
        csr[pos] = (int)(p & 0x1FFFFu);
    }
}

// ---------------- weight transpose+convert: Wt[n][k] = bf16(W[k][n]) ----------------
__global__ __launch_bounds__(128) void wt_kernel(const float* __restrict__ W, u16* __restrict__ Wt) {
    int k = blockIdx.x, n = threadIdx.x;
    Wt[n * HID + k] = bf16r(W[k * HID + n]);
}

// ---------------- f32 VALU GEMM (only for tiny zW table) ----------------
#define FMA4(acc, s, w) { acc.x += (s)*(w).x; acc.y += (s)*(w).y; acc.z += (s)*(w).z; acc.w += (s)*(w).w; }
__global__ __launch_bounds__(256) void gemm128_kernel(
    const float* __restrict__ X, const float* __restrict__ W,
    float* __restrict__ Y, int nrows)
{
    __shared__ float xs[32][132];
    int t = threadIdx.x;
    int row0 = blockIdx.x * 32;
    int sr = t >> 5;
    int sk = (t & 31) * 4;
#pragma unroll
    for (int p = 0; p < 4; ++p) {
        int r = p * 8 + sr;
        int grow = row0 + r;
        float4 v = make_float4(0.f, 0.f, 0.f, 0.f);
        if (grow < nrows) v = *(const float4*)(X + (long)grow * HID + sk);
        *(float4*)(&xs[r][sk]) = v;
    }
    __syncthreads();
    int cg = t & 31, rg = t >> 5;
    int c = cg * 4, r = rg * 4;
    float4 a0 = make_float4(0,0,0,0), a1 = a0, a2 = a0, a3 = a0;
    for (int k = 0; k < 128; k += 4) {
        float x0[4], x1[4], x2[4], x3[4];
        *(float4*)x0 = *(const float4*)&xs[r + 0][k];
        *(float4*)x1 = *(const float4*)&xs[r + 1][k];
        *(float4*)x2 = *(const float4*)&xs[r + 2][k];
        *(float4*)x3 = *(const float4*)&xs[r + 3][k];
#pragma unroll
        for (int j = 0; j < 4; ++j) {
            float4 w = *(const float4*)(W + (k + j) * HID + c);
            FMA4(a0, x0[j], w); FMA4(a1, x1[j], w); FMA4(a2, x2[j], w); FMA4(a3, x3[j], w);
        }
    }
    float4 accs[4] = {a0, a1, a2, a3};
#pragma unroll
    for (int i = 0; i < 4; ++i) {
        int grow = row0 + r + i;
        if (grow < nrows) *(float4*)(Y + (long)grow * HID + c) = accs[i];
    }
}

// ---------------- MFMA bf16 GEMM: Y = Xsrc @ W  (W pre-transposed [N][K] bf16),
// A and W both staged in LDS (proven ~25us form) ----------------
template<int SRC_BF16>
__global__ __launch_bounds__(256) void mfma_gemm_kernel(
    const void* __restrict__ Xsrc,
    const int* __restrict__ gatherIdx,
    const u16* __restrict__ Wt,
    const float* __restrict__ addTab, const int* __restrict__ addIdx,
    u16* __restrict__ Y, int nrows)
{
    __shared__ u16 Als[64][136];
    __shared__ u16 Wls[128][136];
    int t = threadIdx.x;
    int row0 = blockIdx.x * 64;

#pragma unroll
    for (int p = 0; p < 2; ++p) {
        int n = p * 64 + (t >> 2);
        int k0 = (t & 3) * 32;
        const u16* src = Wt + n * HID + k0;
        uint4 v0 = *(const uint4*)(src);
        uint4 v1 = *(const uint4*)(src + 8);
        uint4 v2 = *(const uint4*)(src + 16);
        uint4 v3 = *(const uint4*)(src + 24);
        *(uint4*)&Wls[n][k0]      = v0;
        *(uint4*)&Wls[n][k0 + 8]  = v1;
        *(uint4*)&Wls[n][k0 + 16] = v2;
        *(uint4*)&Wls[n][k0 + 24] = v3;
    }

    if (SRC_BF16) {
        const u16* X = (const u16*)Xsrc;
#pragma unroll
        for (int p = 0; p < 4; ++p) {
            int r = p * 16 + (t >> 4);
            int k0 = (t & 15) * 8;
            int grow = row0 + r;
            uint4 v = make_uint4(0, 0, 0, 0);
            if (grow < nrows) {
                long srow = gatherIdx ? (long)gatherIdx[grow] : (long)grow;
                v = *(const uint4*)(X + srow * HID + k0);
            }
            *(uint4*)&Als[r][k0] = v;
        }
    } else {
        const float* X = (const float*)Xsrc;
#pragma unroll
        for (int p = 0; p < 8; ++p) {
            int r = p * 8 + (t >> 5);
            int k0 = (t & 31) * 4;
            int grow = row0 + r;
            float4 v = make_float4(0.f, 0.f, 0.f, 0.f);
            if (grow < nrows) {
                long srow = gatherIdx ? (long)gatherIdx[grow] : (long)grow;
                v = *(const float4*)(X + srow * HID + k0);
            }
            ushort4 b;
            b.x = bf16r(v.x); b.y = bf16r(v.y); b.z = bf16r(v.z); b.w = bf16r(v.w);
            *(ushort4*)&Als[r][k0] = b;
        }
    }
    __syncthreads();

    int w = t >> 6, l = t & 63;
    int lr = l & 15, lq = l >> 4;
    f32x4 acc[8];
#pragma unroll
    for (int i = 0; i < 8; ++i) acc[i] = (f32x4){0.f, 0.f, 0.f, 0.f};

#pragma unroll
    for (int kk = 0; kk < 4; ++kk) {
        bf16x8 af = *(const bf16x8*)&Als[w * 16 + lr][kk * 32 + lq * 8];
#pragma unroll
        for (int nt = 0; nt < 8; ++nt) {
            bf16x8 bf = *(const bf16x8*)&Wls[nt * 16 + lr][kk * 32 + lq * 8];
            acc[nt] = __builtin_amdgcn_mfma_f32_16x16x32_bf16(af, bf, acc[nt], 0, 0, 0);
        }
    }

    int orow = row0 + w * 16 + lq * 4;
#pragma unroll
    for (int r = 0; r < 4; ++r) {
        int grow = orow + r;
        if (grow < nrows) {
            const float* ap = addTab ? (addTab + (long)addIdx[grow] * HID) : nullptr;
#pragma unroll
            for (int nt = 0; nt < 8; ++nt) {
                int col = nt * 16 + lr;
                float v = acc[nt][r];
                if (ap) v += ap[col];
                Y[(long)grow * HID + col] = bf16r(v);
            }
        }
    }
}

// ---------------- aggregate (bf16 H), 4-deep pipelined gather ----------------
__global__ __launch_bounds__(256) void aggregate_kernel(
    const u16* __restrict__ H, u16* __restrict__ Xo,
    const int* __restrict__ off, const int* __restrict__ csr,
    const float* __restrict__ bias, int n, int doRelu)
{
    int node = blockIdx.x * 4 + (threadIdx.x >> 6);
    if (node >= n) return;
    int lane = threadIdx.x & 63;
    int g = lane >> 4, fl = lane & 15;
    int s = off[node], e = off[node + 1];

    float acc[8] = {0.f, 0.f, 0.f, 0.f, 0.f, 0.f, 0.f, 0.f};
    int j = s + g;

    for (; j + 12 < e; j += 16) {
        int i0 = csr[j];
        int i1 = csr[j + 4];
        int i2 = csr[j + 8];
        int i3 = csr[j + 12];
        uint4 v0 = *(const uint4*)(H + (long)i0 * HID + fl * 8);
        uint4 v1 = *(const uint4*)(H + (long)i1 * HID + fl * 8);
        uint4 v2 = *(const uint4*)(H + (long)i2 * HID + fl * 8);
        uint4 v3 = *(const uint4*)(H + (long)i3 * HID + fl * 8);
        ACC8(v0); ACC8(v1); ACC8(v2); ACC8(v3);
    }
    for (; j + 4 < e; j += 8) {
        int i0 = csr[j];
        int i1 = csr[j + 4];
        uint4 v0 = *(const uint4*)(H + (long)i0 * HID + fl * 8);
        uint4 v1 = *(const uint4*)(H + (long)i1 * HID + fl * 8);
        ACC8(v0); ACC8(v1);
    }
    if (j < e) {
        int i0 = csr[j];
        uint4 v0 = *(const uint4*)(H + (long)i0 * HID + fl * 8);
        ACC8(v0);
    }

#pragma unroll
    for (int i = 0; i < 8; ++i) {
        acc[i] += __shfl_xor(acc[i], 16);
        acc[i] += __shfl_xor(acc[i], 32);
    }

    if (g == 0) {
        uint4 sv = *(const uint4*)(H + (long)node * HID + fl * 8);
        float4 ba = *(const float4*)(bias + fl * 8);
        float4 bb = *(const float4*)(bias + fl * 8 + 4);
        float r[8];
        r[0] = acc[0] + bflo(sv.x) + ba.x;
        r[1] = acc[1] + bfhi(sv.x) + ba.y;
        r[2] = acc[2] + bflo(sv.y) + ba.z;
        r[3] = acc[3] + bfhi(sv.y) + ba.w;
        r[4] = acc[4] + bflo(sv.z) + bb.x;
        r[5] = acc[5] + bfhi(sv.z) + bb.y;
        r[6] = acc[6] + bflo(sv.w) + bb.z;
        r[7] = acc[7] + bfhi(sv.w) + bb.w;
        if (doRelu) {
#pragma unroll
            for (int i = 0; i < 8; ++i) r[i] = fmaxf(r[i], 0.f);
        }
        uint4 ov;
        ov.x = (u32)bf16r(r[0]) | ((u32)bf16r(r[1]) << 16);
        ov.y = (u32)bf16r(r[2]) | ((u32)bf16r(r[3]) << 16);
        ov.z = (u32)bf16r(r[4]) | ((u32)bf16r(r[5]) << 16);
        ov.w = (u32)bf16r(r[6]) | ((u32)bf16r(r[7]) << 16);
        *(uint4*)(Xo + (long)node * HID + fl * 8) = ov;
    }
}

// ---------------- pooling: per-graph mean, coalesced uint4 rows ----------------
__global__ __launch_bounds__(256) void pool_kernel(const u16* __restrict__ X, const int* __restrict__ batch,
                                                   int n, float* __restrict__ pooled) {
    __shared__ float red[4][HID];
    int g = blockIdx.x;
    int t = threadIdx.x;
    int grp = t >> 4, fl = t & 15;
    int lo = 0, hi = n;
    while (lo < hi) { int m = (lo + hi) >> 1; if (batch[m] < g) lo = m + 1; else hi = m; }
    int s = lo;
    lo = 0; hi = n;
    while (lo < hi) { int m = (lo + hi) >> 1; if (batch[m] < g + 1) lo = m + 1; else hi = m; }
    int e = lo;

    float acc[8] = {0.f, 0.f, 0.f, 0.f, 0.f, 0.f, 0.f, 0.f};
    for (int i = s + grp; i < e; i += 16) {
        uint4 v = *(const uint4*)(X + (long)i * HID + fl * 8);
        ACC8(v);
    }
#pragma unroll
    for (int i = 0; i < 8; ++i) {
        acc[i] += __shfl_xor(acc[i], 16);
        acc[i] += __shfl_xor(acc[i], 32);
    }
    int w = t >> 6, lane = t & 63;
    if (lane < 16) {
#pragma unroll
        for (int i = 0; i < 8; ++i) red[w][lane * 8 + i] = acc[i];
    }
    __syncthreads();
    if (t < HID) {
        float v = red[0][t] + red[1][t] + red[2][t] + red[3][t];
        float cnt = (float)(e - s);
        pooled[g * HID + t] = v / fmaxf(cnt, 1.f);
    }
}

// ---------------- MLP head ----------------
__global__ __launch_bounds__(128) void mlp_kernel(
    const float* __restrict__ pooled, const float* __restrict__ W1, const float* __restrict__ b1,
    const float* __restrict__ gamma, const float* __restrict__ beta,
    const float* __restrict__ W2, const float* __restrict__ b2, float* __restrict__ out)
{
    int g = blockIdx.x, t = threadIdx.x;
    __shared__ float p[HID];
    __shared__ float red[4];
    p[t] = pooled[g * HID + t];
    __syncthreads();
    float acc = b1[t];
    for (int k = 0; k < HID; ++k) acc += p[k] * W1[k * HID + t];
    const float inv = 1.0f / sqrtf(1.0f + 1e-5f);
    acc = acc * (gamma[t] * inv) + beta[t];
    acc = fmaxf(acc, 0.f);
    float v0 = acc * W2[t * 2 + 0];
    float v1 = acc * W2[t * 2 + 1];
    for (int d = 32; d > 0; d >>= 1) { v0 += __shfl_down(v0, d); v1 += __shfl_down(v1, d); }
    int w = t >> 6, lane = t & 63;
    if (lane == 0) { red[w * 2] = v0; red[w * 2 + 1] = v1; }
    __syncthreads();
    if (t == 0) {
        out[g * 2 + 0] = red[0] + red[2] + b2[0];
        out[g * 2 + 1] = red[1] + red[3] + b2[1];
    }
}

extern "C" void kernel_launch(void* const* d_in, const int* in_sizes, int n_in,
                              void* d_out, int out_size, void* d_ws, size_t ws_size,
                              hipStream_t stream) {
    const int*   z        = (const int*)d_in[1];
    const int*   ei       = (const int*)d_in[2];
    const int*   batch    = (const int*)d_in[3];
    const int*   node_id  = (const int*)d_in[4];
    const float* z_emb    = (const float*)d_in[5];
    const float* node_emb = (const float*)d_in[6];
    const float* W0  = (const float*)d_in[7];
    const float* b0  = (const float*)d_in[8];
    const float* W1  = (const float*)d_in[9];
    const float* b1  = (const float*)d_in[10];
    const float* W2  = (const float*)d_in[11];
    const float* b2  = (const float*)d_in[12];
    const float* mW1 = (const float*)d_in[13];
    const float* mb1 = (const float*)d_in[14];
    const float* gam = (const float*)d_in[15];
    const float* bet = (const float*)d_in[16];
    const float* mW2 = (const float*)d_in[17];
    const float* mb2 = (const float*)d_in[18];
    float* out = (float*)d_out;

    const int* srcArr = ei;
    const int* dstArr = ei + NE;

    char* ws = (char*)d_ws;
    size_t o = 0;
    auto alloc = [&](size_t bytes) { char* p = ws + o; o += (bytes + 255) & ~(size_t)255; return p; };
    u16*   A      = (u16*)alloc((size_t)NN * HID * 2);
    u16*   B      = (u16*)alloc((size_t)NN * HID * 2);
    float* zW     = (float*)alloc((size_t)MAXZ * HID * 4);
    u16*   W0bt   = (u16*)alloc((size_t)HID * HID * 2);
    u16*   W1t    = (u16*)alloc((size_t)HID * HID * 2);
    u16*   W2t    = (u16*)alloc((size_t)HID * HID * 2);
    int*   bcount = (int*)alloc((size_t)NBK * 4);
    int*   boff   = (int*)alloc((size_t)(NBK + 1) * 4);
    int*   gcur   = (int*)alloc((size_t)NBK * 4);
    u32*   pairs  = (u32*)alloc((size_t)NE * 4);
    int*   off    = (int*)alloc((size_t)(NN + 1) * 4);
    int*   csr    = (int*)alloc((size_t)NE * 4);
    float* pooled = (float*)alloc((size_t)NG * HID * 4);
    (void)ws_size;

    // CSR by dst — staged bucketed build
    hipMemsetAsync(bcount, 0, (size_t)NBK * 4, stream);
    bucket_count_kernel<<<1024, 256, 0, stream>>>(dstArr, bcount);
    scan_nbk_kernel<<<1, NBK, 0, stream>>>(bcount, boff, gcur);
    pair_scatter_kernel<<<(NE + TILE_E - 1) / TILE_E, 256, 0, stream>>>(srcArr, dstArr, gcur, pairs);
    bucket_build_kernel<<<NBK, 256, 0, stream>>>(pairs, boff, off, csr);

    // weights
    wt_kernel<<<HID, HID, 0, stream>>>(W0 + HID * HID, W0bt);
    wt_kernel<<<HID, HID, 0, stream>>>(W1, W1t);
    wt_kernel<<<HID, HID, 0, stream>>>(W2, W2t);

    // zW = z_emb @ W0_top   (f32, tiny)
    gemm128_kernel<<<(MAXZ + 31) / 32, 256, 0, stream>>>(z_emb, W0, zW, MAXZ);

    const int GB = (NN + 63) / 64;
    // layer 0: B = bf16( node_emb[node_id] @ W0_bot + zW[z] )
    mfma_gemm_kernel<0><<<GB, 256, 0, stream>>>(node_emb, node_id, W0bt, zW, z, B, NN);
    aggregate_kernel<<<NN / 4, 256, 0, stream>>>(B, A, off, csr, b0, NN, 1);
    mfma_gemm_kernel<1><<<GB, 256, 0, stream>>>(A, nullptr, W1t, nullptr, nullptr, B, NN);
    aggregate_kernel<<<NN / 4, 256, 0, stream>>>(B, A, off, csr, b1, NN, 1);
    mfma_gemm_kernel<1><<<GB, 256, 0, stream>>>(A, nullptr, W2t, nullptr, nullptr, B, NN);
    aggregate_kernel<<<NN / 4, 256, 0, stream>>>(B, A, off, csr, b2, NN, 0);

    pool_kernel<<<NG, 256, 0, stream>>>(A, batch, NN, pooled);
    mlp_kernel<<<NG, 128, 0, stream>>>(pooled, mW1, mb1, gam, bet, mW2, mb2, out);
}

// Round 11
// 361.671 us; speedup vs baseline: 1.2914x; 1.0450x over previous
//
#include <hip/hip_runtime.h>

#define NN 100000
#define NE 1600000
#define HID 128
#define NG 512
#define MAXZ 1000
#define NBK 256           // dst-range buckets
#define BK_S 391          // nodes per bucket (256*391 = 100096 >= NN)
#define TILE_E 4096       // edges per scatter tile (16/thread)

typedef unsigned short u16;
typedef unsigned int u32;
typedef __attribute__((ext_vector_type(8))) short bf16x8;
typedef __attribute__((ext_vector_type(4))) float f32x4;

__device__ __forceinline__ u16 bf16r(float x) {     // RNE f32->bf16
    u32 u = __float_as_uint(x);
    u32 r = (u + 0x7fffu + ((u >> 16) & 1u)) >> 16;
    return (u16)r;
}
__device__ __forceinline__ float bflo(u32 u) { return __uint_as_float(u << 16); }
__device__ __forceinline__ float bfhi(u32 u) { return __uint_as_float(u & 0xffff0000u); }

#define ACC8(v) { \
    acc[0] += bflo((v).x); acc[1] += bfhi((v).x); \
    acc[2] += bflo((v).y); acc[3] += bfhi((v).y); \
    acc[4] += bflo((v).z); acc[5] += bfhi((v).z); \
    acc[6] += bflo((v).w); acc[7] += bfhi((v).w); }

// ---------------- CSR build ----------------
__global__ __launch_bounds__(256) void bucket_count_kernel(const int* __restrict__ dst,
                                                           int* __restrict__ bcount) {
    __shared__ int lh[NBK];
    int t = threadIdx.x;
    lh[t] = 0;
    __syncthreads();
    int stride = gridDim.x * 256;
    for (int i = blockIdx.x * 256 + t; i < NE; i += stride)
        atomicAdd(&lh[dst[i] / BK_S], 1);
    __syncthreads();
    int v = lh[t];
    if (v) atomicAdd(&bcount[t], v);
}

__global__ __launch_bounds__(NBK) void scan_nbk_kernel(const int* __restrict__ bcount,
                                                       int* __restrict__ boff,
                                                       int* __restrict__ gcursor) {
    __shared__ int buf[NBK];
    int t = threadIdx.x;
    int v = bcount[t];
    buf[t] = v;
    __syncthreads();
    for (int d = 1; d < NBK; d <<= 1) {
        int add = (t >= d) ? buf[t - d] : 0;
        __syncthreads();
        buf[t] += add;
        __syncthreads();
    }
    int excl = buf[t] - v;
    boff[t] = excl;
    gcursor[t] = excl;
    if (t == NBK - 1) boff[NBK] = buf[NBK - 1];
}

__global__ __launch_bounds__(256) void pair_scatter_kernel(const int* __restrict__ src,
                                                           const int* __restrict__ dst,
                                                           int* __restrict__ gcursor,
                                                           u32* __restrict__ pairs) {
    __shared__ int cnt[NBK];
    __shared__ int base[NBK];
    int t = threadIdx.x;
    long tile0 = (long)blockIdx.x * TILE_E;
    cnt[t] = 0;
    __syncthreads();
    u32 val[16], br[16];
#pragma unroll
    for (int i = 0; i < 16; ++i) {
        long idx = tile0 + i * 256 + t;
        val[i] = 0xFFFFFFFFu;
        if (idx < NE) {
            int d = dst[idx];
            int b = d / BK_S;
            int r = atomicAdd(&cnt[b], 1);
            val[i] = ((u32)(d - b * BK_S) << 17) | (u32)src[idx];
            br[i] = ((u32)b << 12) | (u32)r;
        }
    }
    __syncthreads();
    int c = cnt[t];
    if (c) base[t] = atomicAdd(&gcursor[t], c);
    __syncthreads();
#pragma unroll
    for (int i = 0; i < 16; ++i) {
        if (val[i] != 0xFFFFFFFFu) {
            u32 b = br[i] >> 12, r = br[i] & 0xFFFu;
            pairs[base[b] + r] = val[i];
        }
    }
}

__global__ __launch_bounds__(256) void bucket_build_kernel(const u32* __restrict__ pairs,
                                                           const int* __restrict__ boff,
                                                           int* __restrict__ off,
                                                           int* __restrict__ csr) {
    __shared__ int lh[BK_S];
    __shared__ int ts[256];
    int b = blockIdx.x, t = threadIdx.x;
    int base = boff[b], end = boff[b + 1];
    int node0 = b * BK_S;
    for (int i = t; i < BK_S; i += 256) lh[i] = 0;
    __syncthreads();
    for (int j = base + t; j < end; j += 256)
        atomicAdd(&lh[pairs[j] >> 17], 1);
    __syncthreads();
    int i0 = t * 2, i1 = t * 2 + 1;
    int c0 = (i0 < BK_S) ? lh[i0] : 0;
    int c1 = (i1 < BK_S) ? lh[i1] : 0;
    int s = c0 + c1;
    ts[t] = s;
    __syncthreads();
    for (int d = 1; d < 256; d <<= 1) {
        int add = (t >= d) ? ts[t - d] : 0;
        __syncthreads();
        ts[t] += add;
        __syncthreads();
    }
    int e0 = base + ts[t] - s;
    int e1 = e0 + c0;
    if (i0 < BK_S) { lh[i0] = e0; int n = node0 + i0; if (n < NN) off[n] = e0; }
    if (i1 < BK_S) { lh[i1] = e1; int n = node0 + i1; if (n < NN) off[n] = e1; }
    if (b == 0 && t == 0) off[NN] = NE;
    __syncthreads();
    for (int j = base + t; j < end; j += 256) {
        u32 p = pairs[j];
        int pos = atomicAdd(&lh[p >> 17], 1);
        csr[pos] = (int)(p & 0x1FFFFu);
    }
}

// ---------------- weight transpose+convert (W0 bottom + W1 in one launch) ----------------
__global__ __launch_bounds__(128) void wt2_kernel(const float* __restrict__ W0b, const float* __restrict__ W1,
                                                  u16* __restrict__ W0bt, u16* __restrict__ W1t) {
    int k = blockIdx.x & 127;
    int which = blockIdx.x >> 7;
    int n = threadIdx.x;
    const float* W = which ? W1 : W0b;
    u16* o = which ? W1t : W0bt;
    o[n * HID + k] = bf16r(W[k * HID + n]);
}

// ---------------- f32 VALU GEMM (only for tiny zW table) ----------------
#define FMA4(acc, s, w) { acc.x += (s)*(w).x; acc.y += (s)*(w).y; acc.z += (s)*(w).z; acc.w += (s)*(w).w; }
__global__ __launch_bounds__(256) void gemm128_kernel(
    const float* __restrict__ X, const float* __restrict__ W,
    float* __restrict__ Y, int nrows)
{
    __shared__ float xs[32][132];
    int t = threadIdx.x;
    int row0 = blockIdx.x * 32;
    int sr = t >> 5;
    int sk = (t & 31) * 4;
#pragma unroll
    for (int p = 0; p < 4; ++p) {
        int r = p * 8 + sr;
        int grow = row0 + r;
        float4 v = make_float4(0.f, 0.f, 0.f, 0.f);
        if (grow < nrows) v = *(const float4*)(X + (long)grow * HID + sk);
        *(float4*)(&xs[r][sk]) = v;
    }
    __syncthreads();
    int cg = t & 31, rg = t >> 5;
    int c = cg * 4, r = rg * 4;
    float4 a0 = make_float4(0,0,0,0), a1 = a0, a2 = a0, a3 = a0;
    for (int k = 0; k < 128; k += 4) {
        float x0[4], x1[4], x2[4], x3[4];
        *(float4*)x0 = *(const float4*)&xs[r + 0][k];
        *(float4*)x1 = *(const float4*)&xs[r + 1][k];
        *(float4*)x2 = *(const float4*)&xs[r + 2][k];
        *(float4*)x3 = *(const float4*)&xs[r + 3][k];
#pragma unroll
        for (int j = 0; j < 4; ++j) {
            float4 w = *(const float4*)(W + (k + j) * HID + c);
            FMA4(a0, x0[j], w); FMA4(a1, x1[j], w); FMA4(a2, x2[j], w); FMA4(a3, x3[j], w);
        }
    }
    float4 accs[4] = {a0, a1, a2, a3};
#pragma unroll
    for (int i = 0; i < 4; ++i) {
        int grow = row0 + r + i;
        if (grow < nrows) *(float4*)(Y + (long)grow * HID + c) = accs[i];
    }
}

// ---------------- MFMA bf16 GEMM: Y = Xsrc @ W  (W pre-transposed [N][K] bf16),
// A and W both staged in LDS (proven ~25us form) ----------------
template<int SRC_BF16>
__global__ __launch_bounds__(256) void mfma_gemm_kernel(
    const void* __restrict__ Xsrc,
    const int* __restrict__ gatherIdx,
    const u16* __restrict__ Wt,
    const float* __restrict__ addTab, const int* __restrict__ addIdx,
    u16* __restrict__ Y, int nrows)
{
    __shared__ u16 Als[64][136];
    __shared__ u16 Wls[128][136];
    int t = threadIdx.x;
    int row0 = blockIdx.x * 64;

#pragma unroll
    for (int p = 0; p < 2; ++p) {
        int n = p * 64 + (t >> 2);
        int k0 = (t & 3) * 32;
        const u16* src = Wt + n * HID + k0;
        uint4 v0 = *(const uint4*)(src);
        uint4 v1 = *(const uint4*)(src + 8);
        uint4 v2 = *(const uint4*)(src + 16);
        uint4 v3 = *(const uint4*)(src + 24);
        *(uint4*)&Wls[n][k0]      = v0;
        *(uint4*)&Wls[n][k0 + 8]  = v1;
        *(uint4*)&Wls[n][k0 + 16] = v2;
        *(uint4*)&Wls[n][k0 + 24] = v3;
    }

    if (SRC_BF16) {
        const u16* X = (const u16*)Xsrc;
#pragma unroll
        for (int p = 0; p < 4; ++p) {
            int r = p * 16 + (t >> 4);
            int k0 = (t & 15) * 8;
            int grow = row0 + r;
            uint4 v = make_uint4(0, 0, 0, 0);
            if (grow < nrows) {
                long srow = gatherIdx ? (long)gatherIdx[grow] : (long)grow;
                v = *(const uint4*)(X + srow * HID + k0);
            }
            *(uint4*)&Als[r][k0] = v;
        }
    } else {
        const float* X = (const float*)Xsrc;
#pragma unroll
        for (int p = 0; p < 8; ++p) {
            int r = p * 8 + (t >> 5);
            int k0 = (t & 31) * 4;
            int grow = row0 + r;
            float4 v = make_float4(0.f, 0.f, 0.f, 0.f);
            if (grow < nrows) {
                long srow = gatherIdx ? (long)gatherIdx[grow] : (long)grow;
                v = *(const float4*)(X + srow * HID + k0);
            }
            ushort4 b;
            b.x = bf16r(v.x); b.y = bf16r(v.y); b.z = bf16r(v.z); b.w = bf16r(v.w);
            *(ushort4*)&Als[r][k0] = b;
        }
    }
    __syncthreads();

    int w = t >> 6, l = t & 63;
    int lr = l & 15, lq = l >> 4;
    f32x4 acc[8];
#pragma unroll
    for (int i = 0; i < 8; ++i) acc[i] = (f32x4){0.f, 0.f, 0.f, 0.f};

#pragma unroll
    for (int kk = 0; kk < 4; ++kk) {
        bf16x8 af = *(const bf16x8*)&Als[w * 16 + lr][kk * 32 + lq * 8];
#pragma unroll
        for (int nt = 0; nt < 8; ++nt) {
            bf16x8 bf = *(const bf16x8*)&Wls[nt * 16 + lr][kk * 32 + lq * 8];
            acc[nt] = __builtin_amdgcn_mfma_f32_16x16x32_bf16(af, bf, acc[nt], 0, 0, 0);
        }
    }

    int orow = row0 + w * 16 + lq * 4;
#pragma unroll
    for (int r = 0; r < 4; ++r) {
        int grow = orow + r;
        if (grow < nrows) {
            const float* ap = addTab ? (addTab + (long)addIdx[grow] * HID) : nullptr;
#pragma unroll
            for (int nt = 0; nt < 8; ++nt) {
                int col = nt * 16 + lr;
                float v = acc[nt][r];
                if (ap) v += ap[col];
                Y[(long)grow * HID + col] = bf16r(v);
            }
        }
    }
}

// ---------------- aggregate (bf16 H), 4-deep pipelined gather; bias nullable ----------------
__global__ __launch_bounds__(256) void aggregate_kernel(
    const u16* __restrict__ H, u16* __restrict__ Xo,
    const int* __restrict__ off, const int* __restrict__ csr,
    const float* __restrict__ bias, int n, int doRelu)
{
    int node = blockIdx.x * 4 + (threadIdx.x >> 6);
    if (node >= n) return;
    int lane = threadIdx.x & 63;
    int g = lane >> 4, fl = lane & 15;
    int s = off[node], e = off[node + 1];

    float acc[8] = {0.f, 0.f, 0.f, 0.f, 0.f, 0.f, 0.f, 0.f};
    int j = s + g;

    for (; j + 12 < e; j += 16) {
        int i0 = csr[j];
        int i1 = csr[j + 4];
        int i2 = csr[j + 8];
        int i3 = csr[j + 12];
        uint4 v0 = *(const uint4*)(H + (long)i0 * HID + fl * 8);
        uint4 v1 = *(const uint4*)(H + (long)i1 * HID + fl * 8);
        uint4 v2 = *(const uint4*)(H + (long)i2 * HID + fl * 8);
        uint4 v3 = *(const uint4*)(H + (long)i3 * HID + fl * 8);
        ACC8(v0); ACC8(v1); ACC8(v2); ACC8(v3);
    }
    for (; j + 4 < e; j += 8) {
        int i0 = csr[j];
        int i1 = csr[j + 4];
        uint4 v0 = *(const uint4*)(H + (long)i0 * HID + fl * 8);
        uint4 v1 = *(const uint4*)(H + (long)i1 * HID + fl * 8);
        ACC8(v0); ACC8(v1);
    }
    if (j < e) {
        int i0 = csr[j];
        uint4 v0 = *(const uint4*)(H + (long)i0 * HID + fl * 8);
        ACC8(v0);
    }

#pragma unroll
    for (int i = 0; i < 8; ++i) {
        acc[i] += __shfl_xor(acc[i], 16);
        acc[i] += __shfl_xor(acc[i], 32);
    }

    if (g == 0) {
        uint4 sv = *(const uint4*)(H + (long)node * HID + fl * 8);
        float r[8];
        r[0] = acc[0] + bflo(sv.x);
        r[1] = acc[1] + bfhi(sv.x);
        r[2] = acc[2] + bflo(sv.y);
        r[3] = acc[3] + bfhi(sv.y);
        r[4] = acc[4] + bflo(sv.z);
        r[5] = acc[5] + bfhi(sv.z);
        r[6] = acc[6] + bflo(sv.w);
        r[7] = acc[7] + bfhi(sv.w);
        if (bias) {
            float4 ba = *(const float4*)(bias + fl * 8);
            float4 bb = *(const float4*)(bias + fl * 8 + 4);
            r[0] += ba.x; r[1] += ba.y; r[2] += ba.z; r[3] += ba.w;
            r[4] += bb.x; r[5] += bb.y; r[6] += bb.z; r[7] += bb.w;
        }
        if (doRelu) {
#pragma unroll
            for (int i = 0; i < 8; ++i) r[i] = fmaxf(r[i], 0.f);
        }
        uint4 ov;
        ov.x = (u32)bf16r(r[0]) | ((u32)bf16r(r[1]) << 16);
        ov.y = (u32)bf16r(r[2]) | ((u32)bf16r(r[3]) << 16);
        ov.z = (u32)bf16r(r[4]) | ((u32)bf16r(r[5]) << 16);
        ov.w = (u32)bf16r(r[6]) | ((u32)bf16r(r[7]) << 16);
        *(uint4*)(Xo + (long)node * HID + fl * 8) = ov;
    }
}

// ---------------- pooling: per-graph mean, coalesced uint4 rows ----------------
__global__ __launch_bounds__(256) void pool_kernel(const u16* __restrict__ X, const int* __restrict__ batch,
                                                   int n, float* __restrict__ pooled) {
    __shared__ float red[4][HID];
    int g = blockIdx.x;
    int t = threadIdx.x;
    int grp = t >> 4, fl = t & 15;
    int lo = 0, hi = n;
    while (lo < hi) { int m = (lo + hi) >> 1; if (batch[m] < g) lo = m + 1; else hi = m; }
    int s = lo;
    lo = 0; hi = n;
    while (lo < hi) { int m = (lo + hi) >> 1; if (batch[m] < g + 1) lo = m + 1; else hi = m; }
    int e = lo;

    float acc[8] = {0.f, 0.f, 0.f, 0.f, 0.f, 0.f, 0.f, 0.f};
    for (int i = s + grp; i < e; i += 16) {
        uint4 v = *(const uint4*)(X + (long)i * HID + fl * 8);
        ACC8(v);
    }
#pragma unroll
    for (int i = 0; i < 8; ++i) {
        acc[i] += __shfl_xor(acc[i], 16);
        acc[i] += __shfl_xor(acc[i], 32);
    }
    int w = t >> 6, lane = t & 63;
    if (lane < 16) {
#pragma unroll
        for (int i = 0; i < 8; ++i) red[w][lane * 8 + i] = acc[i];
    }
    __syncthreads();
    if (t < HID) {
        float v = red[0][t] + red[1][t] + red[2][t] + red[3][t];
        float cnt = (float)(e - s);
        pooled[g * HID + t] = v / fmaxf(cnt, 1.f);
    }
}

// ---------------- MLP head: pooled = poolT @ W2 + b2 (layer-3 GEMM, hoisted past
// agg+pool by linearity), then Linear -> BN(eval) -> ReLU -> Linear ----------------
__global__ __launch_bounds__(128) void mlp_kernel(
    const float* __restrict__ poolT, const float* __restrict__ W2f, const float* __restrict__ b2,
    const float* __restrict__ W1, const float* __restrict__ b1,
    const float* __restrict__ gamma, const float* __restrict__ beta,
    const float* __restrict__ mW2, const float* __restrict__ mb2, float* __restrict__ out)
{
    int g = blockIdx.x, t = threadIdx.x;
    __shared__ float pt[HID];
    __shared__ float p[HID];
    __shared__ float red[4];
    pt[t] = poolT[g * HID + t];
    __syncthreads();
    // pooled = poolT @ W2 + b2   (f32, replaces the 100k-row layer-3 GEMM)
    float pv = b2[t];
    for (int k = 0; k < HID; ++k) pv += pt[k] * W2f[k * HID + t];
    p[t] = pv;
    __syncthreads();
    float acc = b1[t];
    for (int k = 0; k < HID; ++k) acc += p[k] * W1[k * HID + t];
    const float inv = 1.0f / sqrtf(1.0f + 1e-5f);
    acc = acc * (gamma[t] * inv) + beta[t];
    acc = fmaxf(acc, 0.f);
    float v0 = acc * mW2[t * 2 + 0];
    float v1 = acc * mW2[t * 2 + 1];
    for (int d = 32; d > 0; d >>= 1) { v0 += __shfl_down(v0, d); v1 += __shfl_down(v1, d); }
    int w = t >> 6, lane = t & 63;
    if (lane == 0) { red[w * 2] = v0; red[w * 2 + 1] = v1; }
    __syncthreads();
    if (t == 0) {
        out[g * 2 + 0] = red[0] + red[2] + mb2[0];
        out[g * 2 + 1] = red[1] + red[3] + mb2[1];
    }
}

extern "C" void kernel_launch(void* const* d_in, const int* in_sizes, int n_in,
                              void* d_out, int out_size, void* d_ws, size_t ws_size,
                              hipStream_t stream) {
    const int*   z        = (const int*)d_in[1];
    const int*   ei       = (const int*)d_in[2];
    const int*   batch    = (const int*)d_in[3];
    const int*   node_id  = (const int*)d_in[4];
    const float* z_emb    = (const float*)d_in[5];
    const float* node_emb = (const float*)d_in[6];
    const float* W0  = (const float*)d_in[7];
    const float* b0  = (const float*)d_in[8];
    const float* W1  = (const float*)d_in[9];
    const float* b1  = (const float*)d_in[10];
    const float* W2  = (const float*)d_in[11];
    const float* b2  = (const float*)d_in[12];
    const float* mW1 = (const float*)d_in[13];
    const float* mb1 = (const float*)d_in[14];
    const float* gam = (const float*)d_in[15];
    const float* bet = (const float*)d_in[16];
    const float* mW2 = (const float*)d_in[17];
    const float* mb2 = (const float*)d_in[18];
    float* out = (float*)d_out;

    const int* srcArr = ei;
    const int* dstArr = ei + NE;

    char* ws = (char*)d_ws;
    size_t o = 0;
    auto alloc = [&](size_t bytes) { char* p = ws + o; o += (bytes + 255) & ~(size_t)255; return p; };
    u16*   A      = (u16*)alloc((size_t)NN * HID * 2);
    u16*   B      = (u16*)alloc((size_t)NN * HID * 2);
    float* zW     = (float*)alloc((size_t)MAXZ * HID * 4);
    u16*   W0bt   = (u16*)alloc((size_t)HID * HID * 2);
    u16*   W1t    = (u16*)alloc((size_t)HID * HID * 2);
    int*   bcount = (int*)alloc((size_t)NBK * 4);
    int*   boff   = (int*)alloc((size_t)(NBK + 1) * 4);
    int*   gcur   = (int*)alloc((size_t)NBK * 4);
    u32*   pairs  = (u32*)alloc((size_t)NE * 4);
    int*   off    = (int*)alloc((size_t)(NN + 1) * 4);
    int*   csr    = (int*)alloc((size_t)NE * 4);
    float* poolT  = (float*)alloc((size_t)NG * HID * 4);
    (void)ws_size;

    // CSR by dst — staged bucketed build
    hipMemsetAsync(bcount, 0, (size_t)NBK * 4, stream);
    bucket_count_kernel<<<1024, 256, 0, stream>>>(dstArr, bcount);
    scan_nbk_kernel<<<1, NBK, 0, stream>>>(bcount, boff, gcur);
    pair_scatter_kernel<<<(NE + TILE_E - 1) / TILE_E, 256, 0, stream>>>(srcArr, dstArr, gcur, pairs);
    bucket_build_kernel<<<NBK, 256, 0, stream>>>(pairs, boff, off, csr);

    // weights (W0 bottom half + W1; W2 stays f32 and is applied post-pool)
    wt2_kernel<<<2 * HID, HID, 0, stream>>>(W0 + HID * HID, W1, W0bt, W1t);

    // zW = z_emb @ W0_top   (f32, tiny)
    gemm128_kernel<<<(MAXZ + 31) / 32, 256, 0, stream>>>(z_emb, W0, zW, MAXZ);

    const int GB = (NN + 63) / 64;
    // layer 0: B = bf16( node_emb[node_id] @ W0_bot + zW[z] )
    mfma_gemm_kernel<0><<<GB, 256, 0, stream>>>(node_emb, node_id, W0bt, zW, z, B, NN);
    aggregate_kernel<<<NN / 4, 256, 0, stream>>>(B, A, off, csr, b0, NN, 1);
    // layer 1
    mfma_gemm_kernel<1><<<GB, 256, 0, stream>>>(A, nullptr, W1t, nullptr, nullptr, B, NN);
    aggregate_kernel<<<NN / 4, 256, 0, stream>>>(B, A, off, csr, b1, NN, 1);
    // layer 2: aggregate FIRST (no bias/relu); W2+b2 applied after pool in mlp
    aggregate_kernel<<<NN / 4, 256, 0, stream>>>(A, B, off, csr, nullptr, NN, 0);

    pool_kernel<<<NG, 256, 0, stream>>>(B, batch, NN, poolT);
    mlp_kernel<<<NG, 128, 0, stream>>>(poolT, W2, b2, mW1, mb1, gam, bet, mW2, mb2, out);
}

// Round 12
// 361.640 us; speedup vs baseline: 1.2915x; 1.0001x over previous
//
#include <hip/hip_runtime.h>

#define NN 100000
#define NE 1600000
#define HID 128
#define NG 512
#define MAXZ 1000
#define NBK 256           // dst-range buckets
#define BK_S 391          // nodes per bucket (256*391 = 100096 >= NN)
#define TILE_E 2048       // edges per scatter tile (8/thread)

typedef unsigned short u16;
typedef unsigned int u32;
typedef __attribute__((ext_vector_type(8))) short bf16x8;
typedef __attribute__((ext_vector_type(4))) float f32x4;

__device__ __forceinline__ u16 bf16r(float x) {     // RNE f32->bf16
    u32 u = __float_as_uint(x);
    u32 r = (u + 0x7fffu + ((u >> 16) & 1u)) >> 16;
    return (u16)r;
}
__device__ __forceinline__ float bflo(u32 u) { return __uint_as_float(u << 16); }
__device__ __forceinline__ float bfhi(u32 u) { return __uint_as_float(u & 0xffff0000u); }

#define ACC8(v) { \
    acc[0] += bflo((v).x); acc[1] += bfhi((v).x); \
    acc[2] += bflo((v).y); acc[3] += bfhi((v).y); \
    acc[4] += bflo((v).z); acc[5] += bfhi((v).z); \
    acc[6] += bflo((v).w); acc[7] += bfhi((v).w); }

// ---------------- CSR build ----------------
__global__ __launch_bounds__(256) void bucket_count_kernel(const int* __restrict__ dst,
                                                           int* __restrict__ bcount) {
    __shared__ int lh[NBK];
    int t = threadIdx.x;
    lh[t] = 0;
    __syncthreads();
    int stride = gridDim.x * 256;
    for (int i = blockIdx.x * 256 + t; i < NE; i += stride)
        atomicAdd(&lh[dst[i] / BK_S], 1);
    __syncthreads();
    int v = lh[t];
    if (v) atomicAdd(&bcount[t], v);
}

__global__ __launch_bounds__(NBK) void scan_nbk_kernel(const int* __restrict__ bcount,
                                                       int* __restrict__ boff,
                                                       int* __restrict__ gcursor) {
    __shared__ int buf[NBK];
    int t = threadIdx.x;
    int v = bcount[t];
    buf[t] = v;
    __syncthreads();
    for (int d = 1; d < NBK; d <<= 1) {
        int add = (t >= d) ? buf[t - d] : 0;
        __syncthreads();
        buf[t] += add;
        __syncthreads();
    }
    int excl = buf[t] - v;
    boff[t] = excl;
    gcursor[t] = excl;
    if (t == NBK - 1) boff[NBK] = buf[NBK - 1];
}

__global__ __launch_bounds__(256) void pair_scatter_kernel(const int* __restrict__ src,
                                                           const int* __restrict__ dst,
                                                           int* __restrict__ gcursor,
                                                           u32* __restrict__ pairs) {
    __shared__ int cnt[NBK];
    __shared__ int base[NBK];
    int t = threadIdx.x;
    long tile0 = (long)blockIdx.x * TILE_E;
    cnt[t] = 0;
    __syncthreads();
    u32 val[8], br[8];
#pragma unroll
    for (int i = 0; i < 8; ++i) {
        long idx = tile0 + i * 256 + t;
        val[i] = 0xFFFFFFFFu;
        if (idx < NE) {
            int d = dst[idx];
            int b = d / BK_S;
            int r = atomicAdd(&cnt[b], 1);
            val[i] = ((u32)(d - b * BK_S) << 17) | (u32)src[idx];
            br[i] = ((u32)b << 12) | (u32)r;
        }
    }
    __syncthreads();
    int c = cnt[t];
    if (c) base[t] = atomicAdd(&gcursor[t], c);
    __syncthreads();
#pragma unroll
    for (int i = 0; i < 8; ++i) {
        if (val[i] != 0xFFFFFFFFu) {
            u32 b = br[i] >> 12, r = br[i] & 0xFFFu;
            pairs[base[b] + r] = val[i];
        }
    }
}

__global__ __launch_bounds__(256) void bucket_build_kernel(const u32* __restrict__ pairs,
                                                           const int* __restrict__ boff,
                                                           int* __restrict__ off,
                                                           int* __restrict__ csr) {
    __shared__ int lh[BK_S];
    __shared__ int ts[256];
    int b = blockIdx.x, t = threadIdx.x;
    int base = boff[b], end = boff[b + 1];
    int node0 = b * BK_S;
    for (int i = t; i < BK_S; i += 256) lh[i] = 0;
    __syncthreads();
    for (int j = base + t; j < end; j += 256)
        atomicAdd(&lh[pairs[j] >> 17], 1);
    __syncthreads();
    int i0 = t * 2, i1 = t * 2 + 1;
    int c0 = (i0 < BK_S) ? lh[i0] : 0;
    int c1 = (i1 < BK_S) ? lh[i1] : 0;
    int s = c0 + c1;
    ts[t] = s;
    __syncthreads();
    for (int d = 1; d < 256; d <<= 1) {
        int add = (t >= d) ? ts[t - d] : 0;
        __syncthreads();
        ts[t] += add;
        __syncthreads();
    }
    int e0 = base + ts[t] - s;
    int e1 = e0 + c0;
    if (i0 < BK_S) { lh[i0] = e0; int n = node0 + i0; if (n < NN) off[n] = e0; }
    if (i1 < BK_S) { lh[i1] = e1; int n = node0 + i1; if (n < NN) off[n] = e1; }
    if (b == 0 && t == 0) off[NN] = NE;
    __syncthreads();
    for (int j = base + t; j < end; j += 256) {
        u32 p = pairs[j];
        int pos = atomicAdd(&lh[p >> 17], 1);
        csr[pos] = (int)(p & 0x1FFFFu);
    }
}

// ---------------- weight transpose+convert (W0 bottom + W1 in one launch) ----------------
__global__ __launch_bounds__(128) void wt2_kernel(const float* __restrict__ W0b, const float* __restrict__ W1,
                                                  u16* __restrict__ W0bt, u16* __restrict__ W1t) {
    int k = blockIdx.x & 127;
    int which = blockIdx.x >> 7;
    int n = threadIdx.x;
    const float* W = which ? W1 : W0b;
    u16* o = which ? W1t : W0bt;
    o[n * HID + k] = bf16r(W[k * HID + n]);
}

// ---------------- f32 VALU GEMM (only for tiny zW table) ----------------
#define FMA4(acc, s, w) { acc.x += (s)*(w).x; acc.y += (s)*(w).y; acc.z += (s)*(w).z; acc.w += (s)*(w).w; }
__global__ __launch_bounds__(256) void gemm128_kernel(
    const float* __restrict__ X, const float* __restrict__ W,
    float* __restrict__ Y, int nrows)
{
    __shared__ float xs[32][132];
    int t = threadIdx.x;
    int row0 = blockIdx.x * 32;
    int sr = t >> 5;
    int sk = (t & 31) * 4;
#pragma unroll
    for (int p = 0; p < 4; ++p) {
        int r = p * 8 + sr;
        int grow = row0 + r;
        float4 v = make_float4(0.f, 0.f, 0.f, 0.f);
        if (grow < nrows) v = *(const float4*)(X + (long)grow * HID + sk);
        *(float4*)(&xs[r][sk]) = v;
    }
    __syncthreads();
    int cg = t & 31, rg = t >> 5;
    int c = cg * 4, r = rg * 4;
    float4 a0 = make_float4(0,0,0,0), a1 = a0, a2 = a0, a3 = a0;
    for (int k = 0; k < 128; k += 4) {
        float x0[4], x1[4], x2[4], x3[4];
        *(float4*)x0 = *(const float4*)&xs[r + 0][k];
        *(float4*)x1 = *(const float4*)&xs[r + 1][k];
        *(float4*)x2 = *(const float4*)&xs[r + 2][k];
        *(float4*)x3 = *(const float4*)&xs[r + 3][k];
#pragma unroll
        for (int j = 0; j < 4; ++j) {
            float4 w = *(const float4*)(W + (k + j) * HID + c);
            FMA4(a0, x0[j], w); FMA4(a1, x1[j], w); FMA4(a2, x2[j], w); FMA4(a3, x3[j], w);
        }
    }
    float4 accs[4] = {a0, a1, a2, a3};
#pragma unroll
    for (int i = 0; i < 4; ++i) {
        int grow = row0 + r + i;
        if (grow < nrows) *(float4*)(Y + (long)grow * HID + c) = accs[i];
    }
}

// ---------------- MFMA bf16 GEMM: Y = Xsrc @ W  (W pre-transposed [N][K] bf16),
// A and W both staged in LDS (proven ~25us form) ----------------
template<int SRC_BF16>
__global__ __launch_bounds__(256) void mfma_gemm_kernel(
    const void* __restrict__ Xsrc,
    const int* __restrict__ gatherIdx,
    const u16* __restrict__ Wt,
    const float* __restrict__ addTab, const int* __restrict__ addIdx,
    u16* __restrict__ Y, int nrows)
{
    __shared__ u16 Als[64][136];
    __shared__ u16 Wls[128][136];
    int t = threadIdx.x;
    int row0 = blockIdx.x * 64;

#pragma unroll
    for (int p = 0; p < 2; ++p) {
        int n = p * 64 + (t >> 2);
        int k0 = (t & 3) * 32;
        const u16* src = Wt + n * HID + k0;
        uint4 v0 = *(const uint4*)(src);
        uint4 v1 = *(const uint4*)(src + 8);
        uint4 v2 = *(const uint4*)(src + 16);
        uint4 v3 = *(const uint4*)(src + 24);
        *(uint4*)&Wls[n][k0]      = v0;
        *(uint4*)&Wls[n][k0 + 8]  = v1;
        *(uint4*)&Wls[n][k0 + 16] = v2;
        *(uint4*)&Wls[n][k0 + 24] = v3;
    }

    if (SRC_BF16) {
        const u16* X = (const u16*)Xsrc;
#pragma unroll
        for (int p = 0; p < 4; ++p) {
            int r = p * 16 + (t >> 4);
            int k0 = (t & 15) * 8;
            int grow = row0 + r;
            uint4 v = make_uint4(0, 0, 0, 0);
            if (grow < nrows) {
                long srow = gatherIdx ? (long)gatherIdx[grow] : (long)grow;
                v = *(const uint4*)(X + srow * HID + k0);
            }
            *(uint4*)&Als[r][k0] = v;
        }
    } else {
        const float* X = (const float*)Xsrc;
#pragma unroll
        for (int p = 0; p < 8; ++p) {
            int r = p * 8 + (t >> 5);
            int k0 = (t & 31) * 4;
            int grow = row0 + r;
            float4 v = make_float4(0.f, 0.f, 0.f, 0.f);
            if (grow < nrows) {
                long srow = gatherIdx ? (long)gatherIdx[grow] : (long)grow;
                v = *(const float4*)(X + srow * HID + k0);
            }
            ushort4 b;
            b.x = bf16r(v.x); b.y = bf16r(v.y); b.z = bf16r(v.z); b.w = bf16r(v.w);
            *(ushort4*)&Als[r][k0] = b;
        }
    }
    __syncthreads();

    int w = t >> 6, l = t & 63;
    int lr = l & 15, lq = l >> 4;
    f32x4 acc[8];
#pragma unroll
    for (int i = 0; i < 8; ++i) acc[i] = (f32x4){0.f, 0.f, 0.f, 0.f};

#pragma unroll
    for (int kk = 0; kk < 4; ++kk) {
        bf16x8 af = *(const bf16x8*)&Als[w * 16 + lr][kk * 32 + lq * 8];
#pragma unroll
        for (int nt = 0; nt < 8; ++nt) {
            bf16x8 bf = *(const bf16x8*)&Wls[nt * 16 + lr][kk * 32 + lq * 8];
            acc[nt] = __builtin_amdgcn_mfma_f32_16x16x32_bf16(af, bf, acc[nt], 0, 0, 0);
        }
    }

    int orow = row0 + w * 16 + lq * 4;
#pragma unroll
    for (int r = 0; r < 4; ++r) {
        int grow = orow + r;
        if (grow < nrows) {
            const float* ap = addTab ? (addTab + (long)addIdx[grow] * HID) : nullptr;
#pragma unroll
            for (int nt = 0; nt < 8; ++nt) {
                int col = nt * 16 + lr;
                float v = acc[nt][r];
                if (ap) v += ap[col];
                Y[(long)grow * HID + col] = bf16r(v);
            }
        }
    }
}

// ---------------- aggregate (bf16 H), 4-deep pipelined gather ----------------
__global__ __launch_bounds__(256) void aggregate_kernel(
    const u16* __restrict__ H, u16* __restrict__ Xo,
    const int* __restrict__ off, const int* __restrict__ csr,
    const float* __restrict__ bias, int n, int doRelu)
{
    int node = blockIdx.x * 4 + (threadIdx.x >> 6);
    if (node >= n) return;
    int lane = threadIdx.x & 63;
    int g = lane >> 4, fl = lane & 15;
    int s = off[node], e = off[node + 1];

    float acc[8] = {0.f, 0.f, 0.f, 0.f, 0.f, 0.f, 0.f, 0.f};
    int j = s + g;

    for (; j + 12 < e; j += 16) {
        int i0 = csr[j];
        int i1 = csr[j + 4];
        int i2 = csr[j + 8];
        int i3 = csr[j + 12];
        uint4 v0 = *(const uint4*)(H + (long)i0 * HID + fl * 8);
        uint4 v1 = *(const uint4*)(H + (long)i1 * HID + fl * 8);
        uint4 v2 = *(const uint4*)(H + (long)i2 * HID + fl * 8);
        uint4 v3 = *(const uint4*)(H + (long)i3 * HID + fl * 8);
        ACC8(v0); ACC8(v1); ACC8(v2); ACC8(v3);
    }
    for (; j + 4 < e; j += 8) {
        int i0 = csr[j];
        int i1 = csr[j + 4];
        uint4 v0 = *(const uint4*)(H + (long)i0 * HID + fl * 8);
        uint4 v1 = *(const uint4*)(H + (long)i1 * HID + fl * 8);
        ACC8(v0); ACC8(v1);
    }
    if (j < e) {
        int i0 = csr[j];
        uint4 v0 = *(const uint4*)(H + (long)i0 * HID + fl * 8);
        ACC8(v0);
    }

#pragma unroll
    for (int i = 0; i < 8; ++i) {
        acc[i] += __shfl_xor(acc[i], 16);
        acc[i] += __shfl_xor(acc[i], 32);
    }

    if (g == 0) {
        uint4 sv = *(const uint4*)(H + (long)node * HID + fl * 8);
        float4 ba = *(const float4*)(bias + fl * 8);
        float4 bb = *(const float4*)(bias + fl * 8 + 4);
        float r[8];
        r[0] = acc[0] + bflo(sv.x) + ba.x;
        r[1] = acc[1] + bfhi(sv.x) + ba.y;
        r[2] = acc[2] + bflo(sv.y) + ba.z;
        r[3] = acc[3] + bfhi(sv.y) + ba.w;
        r[4] = acc[4] + bflo(sv.z) + bb.x;
        r[5] = acc[5] + bfhi(sv.z) + bb.y;
        r[6] = acc[6] + bflo(sv.w) + bb.z;
        r[7] = acc[7] + bfhi(sv.w) + bb.w;
        if (doRelu) {
#pragma unroll
            for (int i = 0; i < 8; ++i) r[i] = fmaxf(r[i], 0.f);
        }
        uint4 ov;
        ov.x = (u32)bf16r(r[0]) | ((u32)bf16r(r[1]) << 16);
        ov.y = (u32)bf16r(r[2]) | ((u32)bf16r(r[3]) << 16);
        ov.z = (u32)bf16r(r[4]) | ((u32)bf16r(r[5]) << 16);
        ov.w = (u32)bf16r(r[6]) | ((u32)bf16r(r[7]) << 16);
        *(uint4*)(Xo + (long)node * HID + fl * 8) = ov;
    }
}

// ---------------- fused last layer: pooled_g = [Σ_{i∈g} x_i + Σ_{e:dst∈g} x_src(e)] / n_g
// (agg2+pool merged by linearity; csr is dst-sorted and batch sorted, so each
// graph owns contiguous node range [ns,ne) and edge range [off[ns], off[ne])) ----------------
__global__ __launch_bounds__(256) void edgepool_kernel(
    const u16* __restrict__ X, const int* __restrict__ batch,
    const int* __restrict__ off, const int* __restrict__ csr,
    float* __restrict__ pooled)
{
    __shared__ float red[4][HID];
    int g = blockIdx.x;
    int t = threadIdx.x;
    int grp = t >> 4, fl = t & 15;
    int lo = 0, hi = NN;
    while (lo < hi) { int m = (lo + hi) >> 1; if (batch[m] < g) lo = m + 1; else hi = m; }
    int ns = lo;
    lo = 0; hi = NN;
    while (lo < hi) { int m = (lo + hi) >> 1; if (batch[m] < g + 1) lo = m + 1; else hi = m; }
    int ne = lo;
    int es = off[ns], ee = off[ne];

    float acc[8] = {0.f, 0.f, 0.f, 0.f, 0.f, 0.f, 0.f, 0.f};
    // self rows (streaming)
    for (int i = ns + grp; i < ne; i += 16) {
        uint4 v = *(const uint4*)(X + (long)i * HID + fl * 8);
        ACC8(v);
    }
    // edge gathers, 4-deep pipelined
    int j = es + grp;
    for (; j + 48 < ee; j += 64) {
        int i0 = csr[j];
        int i1 = csr[j + 16];
        int i2 = csr[j + 32];
        int i3 = csr[j + 48];
        uint4 v0 = *(const uint4*)(X + (long)i0 * HID + fl * 8);
        uint4 v1 = *(const uint4*)(X + (long)i1 * HID + fl * 8);
        uint4 v2 = *(const uint4*)(X + (long)i2 * HID + fl * 8);
        uint4 v3 = *(const uint4*)(X + (long)i3 * HID + fl * 8);
        ACC8(v0); ACC8(v1); ACC8(v2); ACC8(v3);
    }
    for (; j < ee; j += 16) {
        int i0 = csr[j];
        uint4 v0 = *(const uint4*)(X + (long)i0 * HID + fl * 8);
        ACC8(v0);
    }

#pragma unroll
    for (int i = 0; i < 8; ++i) {
        acc[i] += __shfl_xor(acc[i], 16);
        acc[i] += __shfl_xor(acc[i], 32);
    }
    int w = t >> 6, lane = t & 63;
    if (lane < 16) {
#pragma unroll
        for (int i = 0; i < 8; ++i) red[w][lane * 8 + i] = acc[i];
    }
    __syncthreads();
    if (t < HID) {
        float v = red[0][t] + red[1][t] + red[2][t] + red[3][t];
        float cnt = (float)(ne - ns);
        pooled[g * HID + t] = v / fmaxf(cnt, 1.f);
    }
}

// ---------------- MLP head: pooled = poolT @ W2 + b2 (layer-3 GEMM hoisted past
// agg+pool by linearity), then Linear -> BN(eval) -> ReLU -> Linear ----------------
__global__ __launch_bounds__(128) void mlp_kernel(
    const float* __restrict__ poolT, const float* __restrict__ W2f, const float* __restrict__ b2,
    const float* __restrict__ W1, const float* __restrict__ b1,
    const float* __restrict__ gamma, const float* __restrict__ beta,
    const float* __restrict__ mW2, const float* __restrict__ mb2, float* __restrict__ out)
{
    int g = blockIdx.x, t = threadIdx.x;
    __shared__ float pt[HID];
    __shared__ float p[HID];
    __shared__ float red[4];
    pt[t] = poolT[g * HID + t];
    __syncthreads();
    float pv = b2[t];
    for (int k = 0; k < HID; ++k) pv += pt[k] * W2f[k * HID + t];
    p[t] = pv;
    __syncthreads();
    float acc = b1[t];
    for (int k = 0; k < HID; ++k) acc += p[k] * W1[k * HID + t];
    const float inv = 1.0f / sqrtf(1.0f + 1e-5f);
    acc = acc * (gamma[t] * inv) + beta[t];
    acc = fmaxf(acc, 0.f);
    float v0 = acc * mW2[t * 2 + 0];
    float v1 = acc * mW2[t * 2 + 1];
    for (int d = 32; d > 0; d >>= 1) { v0 += __shfl_down(v0, d); v1 += __shfl_down(v1, d); }
    int w = t >> 6, lane = t & 63;
    if (lane == 0) { red[w * 2] = v0; red[w * 2 + 1] = v1; }
    __syncthreads();
    if (t == 0) {
        out[g * 2 + 0] = red[0] + red[2] + mb2[0];
        out[g * 2 + 1] = red[1] + red[3] + mb2[1];
    }
}

extern "C" void kernel_launch(void* const* d_in, const int* in_sizes, int n_in,
                              void* d_out, int out_size, void* d_ws, size_t ws_size,
                              hipStream_t stream) {
    const int*   z        = (const int*)d_in[1];
    const int*   ei       = (const int*)d_in[2];
    const int*   batch    = (const int*)d_in[3];
    const int*   node_id  = (const int*)d_in[4];
    const float* z_emb    = (const float*)d_in[5];
    const float* node_emb = (const float*)d_in[6];
    const float* W0  = (const float*)d_in[7];
    const float* b0  = (const float*)d_in[8];
    const float* W1  = (const float*)d_in[9];
    const float* b1  = (const float*)d_in[10];
    const float* W2  = (const float*)d_in[11];
    const float* b2  = (const float*)d_in[12];
    const float* mW1 = (const float*)d_in[13];
    const float* mb1 = (const float*)d_in[14];
    const float* gam = (const float*)d_in[15];
    const float* bet = (const float*)d_in[16];
    const float* mW2 = (const float*)d_in[17];
    const float* mb2 = (const float*)d_in[18];
    float* out = (float*)d_out;

    const int* srcArr = ei;
    const int* dstArr = ei + NE;

    char* ws = (char*)d_ws;
    size_t o = 0;
    auto alloc = [&](size_t bytes) { char* p = ws + o; o += (bytes + 255) & ~(size_t)255; return p; };
    u16*   A      = (u16*)alloc((size_t)NN * HID * 2);
    u16*   B      = (u16*)alloc((size_t)NN * HID * 2);
    float* zW     = (float*)alloc((size_t)MAXZ * HID * 4);
    u16*   W0bt   = (u16*)alloc((size_t)HID * HID * 2);
    u16*   W1t    = (u16*)alloc((size_t)HID * HID * 2);
    int*   bcount = (int*)alloc((size_t)NBK * 4);
    int*   boff   = (int*)alloc((size_t)(NBK + 1) * 4);
    int*   gcur   = (int*)alloc((size_t)NBK * 4);
    u32*   pairs  = (u32*)alloc((size_t)NE * 4);
    int*   off    = (int*)alloc((size_t)(NN + 1) * 4);
    int*   csr    = (int*)alloc((size_t)NE * 4);
    float* poolT  = (float*)alloc((size_t)NG * HID * 4);
    (void)ws_size;

    // CSR by dst — staged bucketed build
    hipMemsetAsync(bcount, 0, (size_t)NBK * 4, stream);
    bucket_count_kernel<<<1024, 256, 0, stream>>>(dstArr, bcount);
    scan_nbk_kernel<<<1, NBK, 0, stream>>>(bcount, boff, gcur);
    pair_scatter_kernel<<<(NE + TILE_E - 1) / TILE_E, 256, 0, stream>>>(srcArr, dstArr, gcur, pairs);
    bucket_build_kernel<<<NBK, 256, 0, stream>>>(pairs, boff, off, csr);

    // weights (W0 bottom half + W1; W2 stays f32 and is applied post-pool)
    wt2_kernel<<<2 * HID, HID, 0, stream>>>(W0 + HID * HID, W1, W0bt, W1t);

    // zW = z_emb @ W0_top   (f32, tiny)
    gemm128_kernel<<<(MAXZ + 31) / 32, 256, 0, stream>>>(z_emb, W0, zW, MAXZ);

    const int GB = (NN + 63) / 64;
    // layer 0: B = bf16( node_emb[node_id] @ W0_bot + zW[z] )
    mfma_gemm_kernel<0><<<GB, 256, 0, stream>>>(node_emb, node_id, W0bt, zW, z, B, NN);
    aggregate_kernel<<<NN / 4, 256, 0, stream>>>(B, A, off, csr, b0, NN, 1);
    // layer 1
    mfma_gemm_kernel<1><<<GB, 256, 0, stream>>>(A, nullptr, W1t, nullptr, nullptr, B, NN);
    aggregate_kernel<<<NN / 4, 256, 0, stream>>>(B, A, off, csr, b1, NN, 1);
    // layer 2 fused with pooling: pooled = pool(x2 + agg(x2)); W2+b2 applied in mlp
    edgepool_kernel<<<NG, 256, 0, stream>>>(A, batch, off, csr, poolT);
    mlp_kernel<<<NG, 128, 0, stream>>>(poolT, W2, b2, mW1, mb1, gam, bet, mW2, mb2, out);
}

// Round 13
// 352.551 us; speedup vs baseline: 1.3248x; 1.0258x over previous
//
#include <hip/hip_runtime.h>

#define NN 100000
#define NE 1600000
#define HID 128
#define NG 512
#define MAXZ 1000
#define NBK 256           // dst-range buckets
#define BK_S 391          // nodes per bucket (256*391 = 100096 >= NN)
#define TILE_E 2048       // edges per scatter tile (8/thread)
#define PSL 8             // pool slices per graph

typedef unsigned short u16;
typedef unsigned int u32;
typedef __attribute__((ext_vector_type(8))) short bf16x8;
typedef __attribute__((ext_vector_type(4))) float f32x4;

__device__ __forceinline__ u16 bf16r(float x) {     // RNE f32->bf16
    u32 u = __float_as_uint(x);
    u32 r = (u + 0x7fffu + ((u >> 16) & 1u)) >> 16;
    return (u16)r;
}
__device__ __forceinline__ float bflo(u32 u) { return __uint_as_float(u << 16); }
__device__ __forceinline__ float bfhi(u32 u) { return __uint_as_float(u & 0xffff0000u); }

#define ACC8(v) { \
    acc[0] += bflo((v).x); acc[1] += bfhi((v).x); \
    acc[2] += bflo((v).y); acc[3] += bfhi((v).y); \
    acc[4] += bflo((v).z); acc[5] += bfhi((v).z); \
    acc[6] += bflo((v).w); acc[7] += bfhi((v).w); }

// ---------------- CSR build ----------------
__global__ __launch_bounds__(256) void bucket_count_kernel(const int* __restrict__ dst,
                                                           int* __restrict__ bcount) {
    __shared__ int lh[NBK];
    int t = threadIdx.x;
    lh[t] = 0;
    __syncthreads();
    int stride = gridDim.x * 256;
    for (int i = blockIdx.x * 256 + t; i < NE; i += stride)
        atomicAdd(&lh[dst[i] / BK_S], 1);
    __syncthreads();
    int v = lh[t];
    if (v) atomicAdd(&bcount[t], v);
}

__global__ __launch_bounds__(NBK) void scan_nbk_kernel(const int* __restrict__ bcount,
                                                       int* __restrict__ boff,
                                                       int* __restrict__ gcursor) {
    __shared__ int buf[NBK];
    int t = threadIdx.x;
    int v = bcount[t];
    buf[t] = v;
    __syncthreads();
    for (int d = 1; d < NBK; d <<= 1) {
        int add = (t >= d) ? buf[t - d] : 0;
        __syncthreads();
        buf[t] += add;
        __syncthreads();
    }
    int excl = buf[t] - v;
    boff[t] = excl;
    gcursor[t] = excl;
    if (t == NBK - 1) boff[NBK] = buf[NBK - 1];
}

__global__ __launch_bounds__(256) void pair_scatter_kernel(const int* __restrict__ src,
                                                           const int* __restrict__ dst,
                                                           int* __restrict__ gcursor,
                                                           u32* __restrict__ pairs) {
    __shared__ int cnt[NBK];
    __shared__ int base[NBK];
    int t = threadIdx.x;
    long tile0 = (long)blockIdx.x * TILE_E;
    cnt[t] = 0;
    __syncthreads();
    u32 val[8], br[8];
#pragma unroll
    for (int i = 0; i < 8; ++i) {
        long idx = tile0 + i * 256 + t;
        val[i] = 0xFFFFFFFFu;
        if (idx < NE) {
            int d = dst[idx];
            int b = d / BK_S;
            int r = atomicAdd(&cnt[b], 1);
            val[i] = ((u32)(d - b * BK_S) << 17) | (u32)src[idx];
            br[i] = ((u32)b << 12) | (u32)r;
        }
    }
    __syncthreads();
    int c = cnt[t];
    if (c) base[t] = atomicAdd(&gcursor[t], c);
    __syncthreads();
#pragma unroll
    for (int i = 0; i < 8; ++i) {
        if (val[i] != 0xFFFFFFFFu) {
            u32 b = br[i] >> 12, r = br[i] & 0xFFFu;
            pairs[base[b] + r] = val[i];
        }
    }
}

__global__ __launch_bounds__(256) void bucket_build_kernel(const u32* __restrict__ pairs,
                                                           const int* __restrict__ boff,
                                                           int* __restrict__ off,
                                                           int* __restrict__ csr) {
    __shared__ int lh[BK_S];
    __shared__ int ts[256];
    int b = blockIdx.x, t = threadIdx.x;
    int base = boff[b], end = boff[b + 1];
    int node0 = b * BK_S;
    for (int i = t; i < BK_S; i += 256) lh[i] = 0;
    __syncthreads();
    for (int j = base + t; j < end; j += 256)
        atomicAdd(&lh[pairs[j] >> 17], 1);
    __syncthreads();
    int i0 = t * 2, i1 = t * 2 + 1;
    int c0 = (i0 < BK_S) ? lh[i0] : 0;
    int c1 = (i1 < BK_S) ? lh[i1] : 0;
    int s = c0 + c1;
    ts[t] = s;
    __syncthreads();
    for (int d = 1; d < 256; d <<= 1) {
        int add = (t >= d) ? ts[t - d] : 0;
        __syncthreads();
        ts[t] += add;
        __syncthreads();
    }
    int e0 = base + ts[t] - s;
    int e1 = e0 + c0;
    if (i0 < BK_S) { lh[i0] = e0; int n = node0 + i0; if (n < NN) off[n] = e0; }
    if (i1 < BK_S) { lh[i1] = e1; int n = node0 + i1; if (n < NN) off[n] = e1; }
    if (b == 0 && t == 0) off[NN] = NE;
    __syncthreads();
    for (int j = base + t; j < end; j += 256) {
        u32 p = pairs[j];
        int pos = atomicAdd(&lh[p >> 17], 1);
        csr[pos] = (int)(p & 0x1FFFFu);
    }
}

// ---------------- weight transpose+convert (W0 bottom + W1 in one launch) ----------------
__global__ __launch_bounds__(128) void wt2_kernel(const float* __restrict__ W0b, const float* __restrict__ W1,
                                                  u16* __restrict__ W0bt, u16* __restrict__ W1t) {
    int k = blockIdx.x & 127;
    int which = blockIdx.x >> 7;
    int n = threadIdx.x;
    const float* W = which ? W1 : W0b;
    u16* o = which ? W1t : W0bt;
    o[n * HID + k] = bf16r(W[k * HID + n]);
}

// ---------------- f32 VALU GEMM (only for tiny zW table) ----------------
#define FMA4(acc, s, w) { acc.x += (s)*(w).x; acc.y += (s)*(w).y; acc.z += (s)*(w).z; acc.w += (s)*(w).w; }
__global__ __launch_bounds__(256) void gemm128_kernel(
    const float* __restrict__ X, const float* __restrict__ W,
    float* __restrict__ Y, int nrows)
{
    __shared__ float xs[32][132];
    int t = threadIdx.x;
    int row0 = blockIdx.x * 32;
    int sr = t >> 5;
    int sk = (t & 31) * 4;
#pragma unroll
    for (int p = 0; p < 4; ++p) {
        int r = p * 8 + sr;
        int grow = row0 + r;
        float4 v = make_float4(0.f, 0.f, 0.f, 0.f);
        if (grow < nrows) v = *(const float4*)(X + (long)grow * HID + sk);
        *(float4*)(&xs[r][sk]) = v;
    }
    __syncthreads();
    int cg = t & 31, rg = t >> 5;
    int c = cg * 4, r = rg * 4;
    float4 a0 = make_float4(0,0,0,0), a1 = a0, a2 = a0, a3 = a0;
    for (int k = 0; k < 128; k += 4) {
        float x0[4], x1[4], x2[4], x3[4];
        *(float4*)x0 = *(const float4*)&xs[r + 0][k];
        *(float4*)x1 = *(const float4*)&xs[r + 1][k];
        *(float4*)x2 = *(const float4*)&xs[r + 2][k];
        *(float4*)x3 = *(const float4*)&xs[r + 3][k];
#pragma unroll
        for (int j = 0; j < 4; ++j) {
            float4 w = *(const float4*)(W + (k + j) * HID + c);
            FMA4(a0, x0[j], w); FMA4(a1, x1[j], w); FMA4(a2, x2[j], w); FMA4(a3, x3[j], w);
        }
    }
    float4 accs[4] = {a0, a1, a2, a3};
#pragma unroll
    for (int i = 0; i < 4; ++i) {
        int grow = row0 + r + i;
        if (grow < nrows) *(float4*)(Y + (long)grow * HID + c) = accs[i];
    }
}

// ---------------- MFMA bf16 GEMM: A + W staged in LDS (proven ~25us form) ----------------
template<int SRC_BF16>
__global__ __launch_bounds__(256) void mfma_gemm_kernel(
    const void* __restrict__ Xsrc,
    const int* __restrict__ gatherIdx,
    const u16* __restrict__ Wt,
    const float* __restrict__ addTab, const int* __restrict__ addIdx,
    u16* __restrict__ Y, int nrows)
{
    __shared__ u16 Als[64][136];
    __shared__ u16 Wls[128][136];
    int t = threadIdx.x;
    int row0 = blockIdx.x * 64;

#pragma unroll
    for (int p = 0; p < 2; ++p) {
        int n = p * 64 + (t >> 2);
        int k0 = (t & 3) * 32;
        const u16* src = Wt + n * HID + k0;
        uint4 v0 = *(const uint4*)(src);
        uint4 v1 = *(const uint4*)(src + 8);
        uint4 v2 = *(const uint4*)(src + 16);
        uint4 v3 = *(const uint4*)(src + 24);
        *(uint4*)&Wls[n][k0]      = v0;
        *(uint4*)&Wls[n][k0 + 8]  = v1;
        *(uint4*)&Wls[n][k0 + 16] = v2;
        *(uint4*)&Wls[n][k0 + 24] = v3;
    }

    if (SRC_BF16) {
        const u16* X = (const u16*)Xsrc;
#pragma unroll
        for (int p = 0; p < 4; ++p) {
            int r = p * 16 + (t >> 4);
            int k0 = (t & 15) * 8;
            int grow = row0 + r;
            uint4 v = make_uint4(0, 0, 0, 0);
            if (grow < nrows) {
                long srow = gatherIdx ? (long)gatherIdx[grow] : (long)grow;
                v = *(const uint4*)(X + srow * HID + k0);
            }
            *(uint4*)&Als[r][k0] = v;
        }
    } else {
        const float* X = (const float*)Xsrc;
#pragma unroll
        for (int p = 0; p < 8; ++p) {
            int r = p * 8 + (t >> 5);
            int k0 = (t & 31) * 4;
            int grow = row0 + r;
            float4 v = make_float4(0.f, 0.f, 0.f, 0.f);
            if (grow < nrows) {
                long srow = gatherIdx ? (long)gatherIdx[grow] : (long)grow;
                v = *(const float4*)(X + srow * HID + k0);
            }
            ushort4 b;
            b.x = bf16r(v.x); b.y = bf16r(v.y); b.z = bf16r(v.z); b.w = bf16r(v.w);
            *(ushort4*)&Als[r][k0] = b;
        }
    }
    __syncthreads();

    int w = t >> 6, l = t & 63;
    int lr = l & 15, lq = l >> 4;
    f32x4 acc[8];
#pragma unroll
    for (int i = 0; i < 8; ++i) acc[i] = (f32x4){0.f, 0.f, 0.f, 0.f};

#pragma unroll
    for (int kk = 0; kk < 4; ++kk) {
        bf16x8 af = *(const bf16x8*)&Als[w * 16 + lr][kk * 32 + lq * 8];
#pragma unroll
        for (int nt = 0; nt < 8; ++nt) {
            bf16x8 bf = *(const bf16x8*)&Wls[nt * 16 + lr][kk * 32 + lq * 8];
            acc[nt] = __builtin_amdgcn_mfma_f32_16x16x32_bf16(af, bf, acc[nt], 0, 0, 0);
        }
    }

    int orow = row0 + w * 16 + lq * 4;
#pragma unroll
    for (int r = 0; r < 4; ++r) {
        int grow = orow + r;
        if (grow < nrows) {
            const float* ap = addTab ? (addTab + (long)addIdx[grow] * HID) : nullptr;
#pragma unroll
            for (int nt = 0; nt < 8; ++nt) {
                int col = nt * 16 + lr;
                float v = acc[nt][r];
                if (ap) v += ap[col];
                Y[(long)grow * HID + col] = bf16r(v);
            }
        }
    }
}

// ---------------- aggregate (bf16 H), 4-deep pipelined gather ----------------
__global__ __launch_bounds__(256) void aggregate_kernel(
    const u16* __restrict__ H, u16* __restrict__ Xo,
    const int* __restrict__ off, const int* __restrict__ csr,
    const float* __restrict__ bias, int n, int doRelu)
{
    int node = blockIdx.x * 4 + (threadIdx.x >> 6);
    if (node >= n) return;
    int lane = threadIdx.x & 63;
    int g = lane >> 4, fl = lane & 15;
    int s = off[node], e = off[node + 1];

    float acc[8] = {0.f, 0.f, 0.f, 0.f, 0.f, 0.f, 0.f, 0.f};
    int j = s + g;

    for (; j + 12 < e; j += 16) {
        int i0 = csr[j];
        int i1 = csr[j + 4];
        int i2 = csr[j + 8];
        int i3 = csr[j + 12];
        uint4 v0 = *(const uint4*)(H + (long)i0 * HID + fl * 8);
        uint4 v1 = *(const uint4*)(H + (long)i1 * HID + fl * 8);
        uint4 v2 = *(const uint4*)(H + (long)i2 * HID + fl * 8);
        uint4 v3 = *(const uint4*)(H + (long)i3 * HID + fl * 8);
        ACC8(v0); ACC8(v1); ACC8(v2); ACC8(v3);
    }
    for (; j + 4 < e; j += 8) {
        int i0 = csr[j];
        int i1 = csr[j + 4];
        uint4 v0 = *(const uint4*)(H + (long)i0 * HID + fl * 8);
        uint4 v1 = *(const uint4*)(H + (long)i1 * HID + fl * 8);
        ACC8(v0); ACC8(v1);
    }
    if (j < e) {
        int i0 = csr[j];
        uint4 v0 = *(const uint4*)(H + (long)i0 * HID + fl * 8);
        ACC8(v0);
    }

#pragma unroll
    for (int i = 0; i < 8; ++i) {
        acc[i] += __shfl_xor(acc[i], 16);
        acc[i] += __shfl_xor(acc[i], 32);
    }

    if (g == 0) {
        uint4 sv = *(const uint4*)(H + (long)node * HID + fl * 8);
        float4 ba = *(const float4*)(bias + fl * 8);
        float4 bb = *(const float4*)(bias + fl * 8 + 4);
        float r[8];
        r[0] = acc[0] + bflo(sv.x) + ba.x;
        r[1] = acc[1] + bfhi(sv.x) + ba.y;
        r[2] = acc[2] + bflo(sv.y) + ba.z;
        r[3] = acc[3] + bfhi(sv.y) + ba.w;
        r[4] = acc[4] + bflo(sv.z) + bb.x;
        r[5] = acc[5] + bfhi(sv.z) + bb.y;
        r[6] = acc[6] + bflo(sv.w) + bb.z;
        r[7] = acc[7] + bfhi(sv.w) + bb.w;
        if (doRelu) {
#pragma unroll
            for (int i = 0; i < 8; ++i) r[i] = fmaxf(r[i], 0.f);
        }
        uint4 ov;
        ov.x = (u32)bf16r(r[0]) | ((u32)bf16r(r[1]) << 16);
        ov.y = (u32)bf16r(r[2]) | ((u32)bf16r(r[3]) << 16);
        ov.z = (u32)bf16r(r[4]) | ((u32)bf16r(r[5]) << 16);
        ov.w = (u32)bf16r(r[6]) | ((u32)bf16r(r[7]) << 16);
        *(uint4*)(Xo + (long)node * HID + fl * 8) = ov;
    }
}

// ---------------- fused last layer, SLICED: poolPart[g][s] = partial sums of
// [Σ_{i∈slice} x_i + Σ_{e∈slice} x_src(e)]; PSL slices/graph for occupancy ----------------
__global__ __launch_bounds__(256) void edgepool_kernel(
    const u16* __restrict__ X, const int* __restrict__ batch,
    const int* __restrict__ off, const int* __restrict__ csr,
    float* __restrict__ poolPart)
{
    __shared__ float red[4][HID];
    int g = blockIdx.x >> 3;          // graph
    int sl = blockIdx.x & (PSL - 1);  // slice
    int t = threadIdx.x;
    int grp = t >> 4, fl = t & 15;
    int lo = 0, hi = NN;
    while (lo < hi) { int m = (lo + hi) >> 1; if (batch[m] < g) lo = m + 1; else hi = m; }
    int ns = lo;
    lo = 0; hi = NN;
    while (lo < hi) { int m = (lo + hi) >> 1; if (batch[m] < g + 1) lo = m + 1; else hi = m; }
    int ne = lo;
    int es = off[ns], ee = off[ne];

    // slice sub-ranges (nodes and edges sliced independently; both are plain sums)
    int nn = ne - ns, en = ee - es;
    int ns0 = ns + (int)((long)nn * sl / PSL);
    int ne0 = ns + (int)((long)nn * (sl + 1) / PSL);
    int es0 = es + (int)((long)en * sl / PSL);
    int ee0 = es + (int)((long)en * (sl + 1) / PSL);

    float acc[8] = {0.f, 0.f, 0.f, 0.f, 0.f, 0.f, 0.f, 0.f};
    for (int i = ns0 + grp; i < ne0; i += 16) {
        uint4 v = *(const uint4*)(X + (long)i * HID + fl * 8);
        ACC8(v);
    }
    int j = es0 + grp;
    for (; j + 48 < ee0; j += 64) {
        int i0 = csr[j];
        int i1 = csr[j + 16];
        int i2 = csr[j + 32];
        int i3 = csr[j + 48];
        uint4 v0 = *(const uint4*)(X + (long)i0 * HID + fl * 8);
        uint4 v1 = *(const uint4*)(X + (long)i1 * HID + fl * 8);
        uint4 v2 = *(const uint4*)(X + (long)i2 * HID + fl * 8);
        uint4 v3 = *(const uint4*)(X + (long)i3 * HID + fl * 8);
        ACC8(v0); ACC8(v1); ACC8(v2); ACC8(v3);
    }
    for (; j < ee0; j += 16) {
        int i0 = csr[j];
        uint4 v0 = *(const uint4*)(X + (long)i0 * HID + fl * 8);
        ACC8(v0);
    }

#pragma unroll
    for (int i = 0; i < 8; ++i) {
        acc[i] += __shfl_xor(acc[i], 16);
        acc[i] += __shfl_xor(acc[i], 32);
    }
    int w = t >> 6, lane = t & 63;
    if (lane < 16) {
#pragma unroll
        for (int i = 0; i < 8; ++i) red[w][lane * 8 + i] = acc[i];
    }
    __syncthreads();
    if (t < HID) {
        float v = red[0][t] + red[1][t] + red[2][t] + red[3][t];
        poolPart[((long)g * PSL + sl) * HID + t] = v;
    }
}

// ---------------- MLP head: sum slices, /n_g, @W2+b2 (hoisted layer-3), MLP ----------------
__global__ __launch_bounds__(128) void mlp_kernel(
    const float* __restrict__ poolPart, const int* __restrict__ batch,
    const float* __restrict__ W2f, const float* __restrict__ b2,
    const float* __restrict__ W1, const float* __restrict__ b1,
    const float* __restrict__ gamma, const float* __restrict__ beta,
    const float* __restrict__ mW2, const float* __restrict__ mb2, float* __restrict__ out)
{
    int g = blockIdx.x, t = threadIdx.x;
    __shared__ float pt[HID];
    __shared__ float p[HID];
    __shared__ float red[4];
    int lo = 0, hi = NN;
    while (lo < hi) { int m = (lo + hi) >> 1; if (batch[m] < g) lo = m + 1; else hi = m; }
    int ns = lo;
    lo = 0; hi = NN;
    while (lo < hi) { int m = (lo + hi) >> 1; if (batch[m] < g + 1) lo = m + 1; else hi = m; }
    float cnt = fmaxf((float)(lo - ns), 1.f);

    float v = 0.f;
#pragma unroll
    for (int s = 0; s < PSL; ++s) v += poolPart[((long)g * PSL + s) * HID + t];
    pt[t] = v / cnt;
    __syncthreads();
    float pv = b2[t];
    for (int k = 0; k < HID; ++k) pv += pt[k] * W2f[k * HID + t];
    p[t] = pv;
    __syncthreads();
    float acc = b1[t];
    for (int k = 0; k < HID; ++k) acc += p[k] * W1[k * HID + t];
    const float inv = 1.0f / sqrtf(1.0f + 1e-5f);
    acc = acc * (gamma[t] * inv) + beta[t];
    acc = fmaxf(acc, 0.f);
    float v0 = acc * mW2[t * 2 + 0];
    float v1 = acc * mW2[t * 2 + 1];
    for (int d = 32; d > 0; d >>= 1) { v0 += __shfl_down(v0, d); v1 += __shfl_down(v1, d); }
    int w = t >> 6, lane = t & 63;
    if (lane == 0) { red[w * 2] = v0; red[w * 2 + 1] = v1; }
    __syncthreads();
    if (t == 0) {
        out[g * 2 + 0] = red[0] + red[2] + mb2[0];
        out[g * 2 + 1] = red[1] + red[3] + mb2[1];
    }
}

extern "C" void kernel_launch(void* const* d_in, const int* in_sizes, int n_in,
                              void* d_out, int out_size, void* d_ws, size_t ws_size,
                              hipStream_t stream) {
    const int*   z        = (const int*)d_in[1];
    const int*   ei       = (const int*)d_in[2];
    const int*   batch    = (const int*)d_in[3];
    const int*   node_id  = (const int*)d_in[4];
    const float* z_emb    = (const float*)d_in[5];
    const float* node_emb = (const float*)d_in[6];
    const float* W0  = (const float*)d_in[7];
    const float* b0  = (const float*)d_in[8];
    const float* W1  = (const float*)d_in[9];
    const float* b1  = (const float*)d_in[10];
    const float* W2  = (const float*)d_in[11];
    const float* b2  = (const float*)d_in[12];
    const float* mW1 = (const float*)d_in[13];
    const float* mb1 = (const float*)d_in[14];
    const float* gam = (const float*)d_in[15];
    const float* bet = (const float*)d_in[16];
    const float* mW2 = (const float*)d_in[17];
    const float* mb2 = (const float*)d_in[18];
    float* out = (float*)d_out;

    const int* srcArr = ei;
    const int* dstArr = ei + NE;

    char* ws = (char*)d_ws;
    size_t o = 0;
    auto alloc = [&](size_t bytes) { char* p = ws + o; o += (bytes + 255) & ~(size_t)255; return p; };
    u16*   A      = (u16*)alloc((size_t)NN * HID * 2);
    u16*   B      = (u16*)alloc((size_t)NN * HID * 2);
    float* zW     = (float*)alloc((size_t)MAXZ * HID * 4);
    u16*   W0bt   = (u16*)alloc((size_t)HID * HID * 2);
    u16*   W1t    = (u16*)alloc((size_t)HID * HID * 2);
    int*   bcount = (int*)alloc((size_t)NBK * 4);
    int*   boff   = (int*)alloc((size_t)(NBK + 1) * 4);
    int*   gcur   = (int*)alloc((size_t)NBK * 4);
    u32*   pairs  = (u32*)alloc((size_t)NE * 4);
    int*   off    = (int*)alloc((size_t)(NN + 1) * 4);
    int*   csr    = (int*)alloc((size_t)NE * 4);
    float* poolP  = (float*)alloc((size_t)NG * PSL * HID * 4);
    (void)ws_size;

    // CSR by dst — staged bucketed build
    hipMemsetAsync(bcount, 0, (size_t)NBK * 4, stream);
    bucket_count_kernel<<<1024, 256, 0, stream>>>(dstArr, bcount);
    scan_nbk_kernel<<<1, NBK, 0, stream>>>(bcount, boff, gcur);
    pair_scatter_kernel<<<(NE + TILE_E - 1) / TILE_E, 256, 0, stream>>>(srcArr, dstArr, gcur, pairs);
    bucket_build_kernel<<<NBK, 256, 0, stream>>>(pairs, boff, off, csr);

    // weights (W0 bottom half + W1; W2 stays f32 and is applied post-pool)
    wt2_kernel<<<2 * HID, HID, 0, stream>>>(W0 + HID * HID, W1, W0bt, W1t);

    // zW = z_emb @ W0_top   (f32, tiny)
    gemm128_kernel<<<(MAXZ + 31) / 32, 256, 0, stream>>>(z_emb, W0, zW, MAXZ);

    const int GB = (NN + 63) / 64;
    // layer 0: B = bf16( node_emb[node_id] @ W0_bot + zW[z] )
    mfma_gemm_kernel<0><<<GB, 256, 0, stream>>>(node_emb, node_id, W0bt, zW, z, B, NN);
    aggregate_kernel<<<NN / 4, 256, 0, stream>>>(B, A, off, csr, b0, NN, 1);
    // layer 1
    mfma_gemm_kernel<1><<<GB, 256, 0, stream>>>(A, nullptr, W1t, nullptr, nullptr, B, NN);
    aggregate_kernel<<<NN / 4, 256, 0, stream>>>(B, A, off, csr, b1, NN, 1);
    // layer 2 fused with pooling (sliced): partials of pool(x2 + agg(x2))
    edgepool_kernel<<<NG * PSL, 256, 0, stream>>>(A, batch, off, csr, poolP);
    mlp_kernel<<<NG, 128, 0, stream>>>(poolP, batch, W2, b2, mW1, mb1, gam, bet, mW2, mb2, out);
}

// Round 14
// 335.315 us; speedup vs baseline: 1.3929x; 1.0514x over previous
//
#include <hip/hip_runtime.h>

#define NN 100000
#define NE 1600000
#define HID 128
#define NG 512
#define MAXZ 1000
#define NBK 256           // dst-range buckets
#define BK_S 391          // nodes per bucket (256*391 = 100096 >= NN)
#define TILE_E 2048       // edges per scatter tile (8/thread)
#define CAP 8192          // fixed slots per bucket (mean 6250, +24 sigma slack)
#define PSL 8             // pool slices per graph

typedef unsigned short u16;
typedef unsigned int u32;
typedef __attribute__((ext_vector_type(8))) short bf16x8;
typedef __attribute__((ext_vector_type(4))) float f32x4;

__device__ __forceinline__ u16 bf16r(float x) {     // RNE f32->bf16
    u32 u = __float_as_uint(x);
    u32 r = (u + 0x7fffu + ((u >> 16) & 1u)) >> 16;
    return (u16)r;
}
__device__ __forceinline__ float bflo(u32 u) { return __uint_as_float(u << 16); }
__device__ __forceinline__ float bfhi(u32 u) { return __uint_as_float(u & 0xffff0000u); }

#define ACC8(v) { \
    acc[0] += bflo((v).x); acc[1] += bfhi((v).x); \
    acc[2] += bflo((v).y); acc[3] += bfhi((v).y); \
    acc[4] += bflo((v).z); acc[5] += bfhi((v).z); \
    acc[6] += bflo((v).w); acc[7] += bfhi((v).w); }

// ---------------- CSR build (fixed-capacity buckets: no count/scan prepass) ----------------
__global__ __launch_bounds__(256) void pair_scatter_kernel(const int* __restrict__ src,
                                                           const int* __restrict__ dst,
                                                           int* __restrict__ gcount,
                                                           u32* __restrict__ pairs) {
    __shared__ int cnt[NBK];
    __shared__ int base[NBK];
    int t = threadIdx.x;
    long tile0 = (long)blockIdx.x * TILE_E;
    cnt[t] = 0;
    __syncthreads();
    u32 val[8], br[8];
#pragma unroll
    for (int i = 0; i < 8; ++i) {
        long idx = tile0 + i * 256 + t;
        val[i] = 0xFFFFFFFFu;
        if (idx < NE) {
            int d = dst[idx];
            int b = d / BK_S;
            int r = atomicAdd(&cnt[b], 1);      // within-tile rank, < 2048
            val[i] = ((u32)(d - b * BK_S) << 17) | (u32)src[idx];
            br[i] = ((u32)b << 12) | (u32)r;
        }
    }
    __syncthreads();
    int c = cnt[t];
    if (c) base[t] = atomicAdd(&gcount[t], c);
    __syncthreads();
#pragma unroll
    for (int i = 0; i < 8; ++i) {
        if (val[i] != 0xFFFFFFFFu) {
            u32 b = br[i] >> 12, r = br[i] & 0xFFFu;
            pairs[(long)b * CAP + base[b] + r] = val[i];
        }
    }
}

// per-bucket: LDS hist + scan -> off[]/end[]; LDS-cursor scatter -> csr (gapped layout)
__global__ __launch_bounds__(256) void bucket_build_kernel(const u32* __restrict__ pairs,
                                                           const int* __restrict__ gcount,
                                                           int* __restrict__ off,
                                                           int* __restrict__ endA,
                                                           int* __restrict__ csr) {
    __shared__ int lh[BK_S];
    __shared__ int ts[256];
    int b = blockIdx.x, t = threadIdx.x;
    int base = b * CAP;
    int cnt = gcount[b];
    int node0 = b * BK_S;
    for (int i = t; i < BK_S; i += 256) lh[i] = 0;
    __syncthreads();
    for (int j = t; j < cnt; j += 256)
        atomicAdd(&lh[pairs[base + j] >> 17], 1);
    __syncthreads();
    int i0 = t * 2, i1 = t * 2 + 1;
    int c0 = (i0 < BK_S) ? lh[i0] : 0;
    int c1 = (i1 < BK_S) ? lh[i1] : 0;
    int s = c0 + c1;
    ts[t] = s;
    __syncthreads();
    for (int d = 1; d < 256; d <<= 1) {
        int add = (t >= d) ? ts[t - d] : 0;
        __syncthreads();
        ts[t] += add;
        __syncthreads();
    }
    int e0 = base + ts[t] - s;
    int e1 = e0 + c0;
    if (i0 < BK_S) { lh[i0] = e0; int n = node0 + i0; if (n < NN) { off[n] = e0; endA[n] = e0 + c0; } }
    if (i1 < BK_S) { lh[i1] = e1; int n = node0 + i1; if (n < NN) { off[n] = e1; endA[n] = e1 + c1; } }
    __syncthreads();
    for (int j = t; j < cnt; j += 256) {
        u32 p = pairs[base + j];
        int pos = atomicAdd(&lh[p >> 17], 1);
        csr[pos] = (int)(p & 0x1FFFFu);
    }
}

// ---------------- weight transpose+convert (W0 bottom + W1 in one launch) ----------------
__global__ __launch_bounds__(128) void wt2_kernel(const float* __restrict__ W0b, const float* __restrict__ W1,
                                                  u16* __restrict__ W0bt, u16* __restrict__ W1t) {
    int k = blockIdx.x & 127;
    int which = blockIdx.x >> 7;
    int n = threadIdx.x;
    const float* W = which ? W1 : W0b;
    u16* o = which ? W1t : W0bt;
    o[n * HID + k] = bf16r(W[k * HID + n]);
}

// ---------------- f32 VALU GEMM (only for tiny zW table) ----------------
#define FMA4(acc, s, w) { acc.x += (s)*(w).x; acc.y += (s)*(w).y; acc.z += (s)*(w).z; acc.w += (s)*(w).w; }
__global__ __launch_bounds__(256) void gemm128_kernel(
    const float* __restrict__ X, const float* __restrict__ W,
    float* __restrict__ Y, int nrows)
{
    __shared__ float xs[32][132];
    int t = threadIdx.x;
    int row0 = blockIdx.x * 32;
    int sr = t >> 5;
    int sk = (t & 31) * 4;
#pragma unroll
    for (int p = 0; p < 4; ++p) {
        int r = p * 8 + sr;
        int grow = row0 + r;
        float4 v = make_float4(0.f, 0.f, 0.f, 0.f);
        if (grow < nrows) v = *(const float4*)(X + (long)grow * HID + sk);
        *(float4*)(&xs[r][sk]) = v;
    }
    __syncthreads();
    int cg = t & 31, rg = t >> 5;
    int c = cg * 4, r = rg * 4;
    float4 a0 = make_float4(0,0,0,0), a1 = a0, a2 = a0, a3 = a0;
    for (int k = 0; k < 128; k += 4) {
        float x0[4], x1[4], x2[4], x3[4];
        *(float4*)x0 = *(const float4*)&xs[r + 0][k];
        *(float4*)x1 = *(const float4*)&xs[r + 1][k];
        *(float4*)x2 = *(const float4*)&xs[r + 2][k];
        *(float4*)x3 = *(const float4*)&xs[r + 3][k];
#pragma unroll
        for (int j = 0; j < 4; ++j) {
            float4 w = *(const float4*)(W + (k + j) * HID + c);
            FMA4(a0, x0[j], w); FMA4(a1, x1[j], w); FMA4(a2, x2[j], w); FMA4(a3, x3[j], w);
        }
    }
    float4 accs[4] = {a0, a1, a2, a3};
#pragma unroll
    for (int i = 0; i < 4; ++i) {
        int grow = row0 + r + i;
        if (grow < nrows) *(float4*)(Y + (long)grow * HID + c) = accs[i];
    }
}

// ---------------- MFMA bf16 GEMM: A + W staged in LDS (proven ~25us form) ----------------
template<int SRC_BF16>
__global__ __launch_bounds__(256) void mfma_gemm_kernel(
    const void* __restrict__ Xsrc,
    const int* __restrict__ gatherIdx,
    const u16* __restrict__ Wt,
    const float* __restrict__ addTab, const int* __restrict__ addIdx,
    u16* __restrict__ Y, int nrows)
{
    __shared__ u16 Als[64][136];
    __shared__ u16 Wls[128][136];
    int t = threadIdx.x;
    int row0 = blockIdx.x * 64;

#pragma unroll
    for (int p = 0; p < 2; ++p) {
        int n = p * 64 + (t >> 2);
        int k0 = (t & 3) * 32;
        const u16* src = Wt + n * HID + k0;
        uint4 v0 = *(const uint4*)(src);
        uint4 v1 = *(const uint4*)(src + 8);
        uint4 v2 = *(const uint4*)(src + 16);
        uint4 v3 = *(const uint4*)(src + 24);
        *(uint4*)&Wls[n][k0]      = v0;
        *(uint4*)&Wls[n][k0 + 8]  = v1;
        *(uint4*)&Wls[n][k0 + 16] = v2;
        *(uint4*)&Wls[n][k0 + 24] = v3;
    }

    if (SRC_BF16) {
        const u16* X = (const u16*)Xsrc;
#pragma unroll
        for (int p = 0; p < 4; ++p) {
            int r = p * 16 + (t >> 4);
            int k0 = (t & 15) * 8;
            int grow = row0 + r;
            uint4 v = make_uint4(0, 0, 0, 0);
            if (grow < nrows) {
                long srow = gatherIdx ? (long)gatherIdx[grow] : (long)grow;
                v = *(const uint4*)(X + srow * HID + k0);
            }
            *(uint4*)&Als[r][k0] = v;
        }
    } else {
        const float* X = (const float*)Xsrc;
#pragma unroll
        for (int p = 0; p < 8; ++p) {
            int r = p * 8 + (t >> 5);
            int k0 = (t & 31) * 4;
            int grow = row0 + r;
            float4 v = make_float4(0.f, 0.f, 0.f, 0.f);
            if (grow < nrows) {
                long srow = gatherIdx ? (long)gatherIdx[grow] : (long)grow;
                v = *(const float4*)(X + srow * HID + k0);
            }
            ushort4 b;
            b.x = bf16r(v.x); b.y = bf16r(v.y); b.z = bf16r(v.z); b.w = bf16r(v.w);
            *(ushort4*)&Als[r][k0] = b;
        }
    }
    __syncthreads();

    int w = t >> 6, l = t & 63;
    int lr = l & 15, lq = l >> 4;
    f32x4 acc[8];
#pragma unroll
    for (int i = 0; i < 8; ++i) acc[i] = (f32x4){0.f, 0.f, 0.f, 0.f};

#pragma unroll
    for (int kk = 0; kk < 4; ++kk) {
        bf16x8 af = *(const bf16x8*)&Als[w * 16 + lr][kk * 32 + lq * 8];
#pragma unroll
        for (int nt = 0; nt < 8; ++nt) {
            bf16x8 bf = *(const bf16x8*)&Wls[nt * 16 + lr][kk * 32 + lq * 8];
            acc[nt] = __builtin_amdgcn_mfma_f32_16x16x32_bf16(af, bf, acc[nt], 0, 0, 0);
        }
    }

    int orow = row0 + w * 16 + lq * 4;
#pragma unroll
    for (int r = 0; r < 4; ++r) {
        int grow = orow + r;
        if (grow < nrows) {
            const float* ap = addTab ? (addTab + (long)addIdx[grow] * HID) : nullptr;
#pragma unroll
            for (int nt = 0; nt < 8; ++nt) {
                int col = nt * 16 + lr;
                float v = acc[nt][r];
                if (ap) v += ap[col];
                Y[(long)grow * HID + col] = bf16r(v);
            }
        }
    }
}

// ---------------- aggregate (bf16 H), 4-deep pipelined gather; gapped csr ----------------
__global__ __launch_bounds__(256) void aggregate_kernel(
    const u16* __restrict__ H, u16* __restrict__ Xo,
    const int* __restrict__ off, const int* __restrict__ endA, const int* __restrict__ csr,
    const float* __restrict__ bias, int n, int doRelu)
{
    int node = blockIdx.x * 4 + (threadIdx.x >> 6);
    if (node >= n) return;
    int lane = threadIdx.x & 63;
    int g = lane >> 4, fl = lane & 15;
    int s = off[node], e = endA[node];

    float acc[8] = {0.f, 0.f, 0.f, 0.f, 0.f, 0.f, 0.f, 0.f};
    int j = s + g;

    for (; j + 12 < e; j += 16) {
        int i0 = csr[j];
        int i1 = csr[j + 4];
        int i2 = csr[j + 8];
        int i3 = csr[j + 12];
        uint4 v0 = *(const uint4*)(H + (long)i0 * HID + fl * 8);
        uint4 v1 = *(const uint4*)(H + (long)i1 * HID + fl * 8);
        uint4 v2 = *(const uint4*)(H + (long)i2 * HID + fl * 8);
        uint4 v3 = *(const uint4*)(H + (long)i3 * HID + fl * 8);
        ACC8(v0); ACC8(v1); ACC8(v2); ACC8(v3);
    }
    for (; j + 4 < e; j += 8) {
        int i0 = csr[j];
        int i1 = csr[j + 4];
        uint4 v0 = *(const uint4*)(H + (long)i0 * HID + fl * 8);
        uint4 v1 = *(const uint4*)(H + (long)i1 * HID + fl * 8);
        ACC8(v0); ACC8(v1);
    }
    if (j < e) {
        int i0 = csr[j];
        uint4 v0 = *(const uint4*)(H + (long)i0 * HID + fl * 8);
        ACC8(v0);
    }

#pragma unroll
    for (int i = 0; i < 8; ++i) {
        acc[i] += __shfl_xor(acc[i], 16);
        acc[i] += __shfl_xor(acc[i], 32);
    }

    if (g == 0) {
        uint4 sv = *(const uint4*)(H + (long)node * HID + fl * 8);
        float4 ba = *(const float4*)(bias + fl * 8);
        float4 bb = *(const float4*)(bias + fl * 8 + 4);
        float r[8];
        r[0] = acc[0] + bflo(sv.x) + ba.x;
        r[1] = acc[1] + bfhi(sv.x) + ba.y;
        r[2] = acc[2] + bflo(sv.y) + ba.z;
        r[3] = acc[3] + bfhi(sv.y) + ba.w;
        r[4] = acc[4] + bflo(sv.z) + bb.x;
        r[5] = acc[5] + bfhi(sv.z) + bb.y;
        r[6] = acc[6] + bflo(sv.w) + bb.z;
        r[7] = acc[7] + bfhi(sv.w) + bb.w;
        if (doRelu) {
#pragma unroll
            for (int i = 0; i < 8; ++i) r[i] = fmaxf(r[i], 0.f);
        }
        uint4 ov;
        ov.x = (u32)bf16r(r[0]) | ((u32)bf16r(r[1]) << 16);
        ov.y = (u32)bf16r(r[2]) | ((u32)bf16r(r[3]) << 16);
        ov.z = (u32)bf16r(r[4]) | ((u32)bf16r(r[5]) << 16);
        ov.w = (u32)bf16r(r[6]) | ((u32)bf16r(r[7]) << 16);
        *(uint4*)(Xo + (long)node * HID + fl * 8) = ov;
    }
}

// ---------------- fused last layer, SLICED + node-major (gapped csr):
// poolPart[g][s] = Σ_{i∈node-slice} [ x_i + Σ_{e:dst=i} x_src(e) ] ----------------
__global__ __launch_bounds__(256) void edgepool_kernel(
    const u16* __restrict__ X, const int* __restrict__ batch,
    const int* __restrict__ off, const int* __restrict__ endA, const int* __restrict__ csr,
    float* __restrict__ poolPart)
{
    __shared__ float red[4][HID];
    int g = blockIdx.x >> 3;          // graph
    int sl = blockIdx.x & (PSL - 1);  // slice
    int t = threadIdx.x;
    int grp = t >> 4, fl = t & 15;
    int lo = 0, hi = NN;
    while (lo < hi) { int m = (lo + hi) >> 1; if (batch[m] < g) lo = m + 1; else hi = m; }
    int ns = lo;
    lo = 0; hi = NN;
    while (lo < hi) { int m = (lo + hi) >> 1; if (batch[m] < g + 1) lo = m + 1; else hi = m; }
    int ne = lo;
    int nn = ne - ns;
    int ns0 = ns + (int)((long)nn * sl / PSL);
    int ne0 = ns + (int)((long)nn * (sl + 1) / PSL);

    float acc[8] = {0.f, 0.f, 0.f, 0.f, 0.f, 0.f, 0.f, 0.f};
    for (int i = ns0 + grp; i < ne0; i += 16) {
        uint4 v = *(const uint4*)(X + (long)i * HID + fl * 8);   // self
        ACC8(v);
        int s = off[i], e = endA[i];
        int j = s;
        for (; j + 3 < e; j += 4) {
            int i0 = csr[j];
            int i1 = csr[j + 1];
            int i2 = csr[j + 2];
            int i3 = csr[j + 3];
            uint4 v0 = *(const uint4*)(X + (long)i0 * HID + fl * 8);
            uint4 v1 = *(const uint4*)(X + (long)i1 * HID + fl * 8);
            uint4 v2 = *(const uint4*)(X + (long)i2 * HID + fl * 8);
            uint4 v3 = *(const uint4*)(X + (long)i3 * HID + fl * 8);
            ACC8(v0); ACC8(v1); ACC8(v2); ACC8(v3);
        }
        for (; j < e; ++j) {
            int i0 = csr[j];
            uint4 v0 = *(const uint4*)(X + (long)i0 * HID + fl * 8);
            ACC8(v0);
        }
    }

#pragma unroll
    for (int i = 0; i < 8; ++i) {
        acc[i] += __shfl_xor(acc[i], 16);
        acc[i] += __shfl_xor(acc[i], 32);
    }
    int w = t >> 6, lane = t & 63;
    if (lane < 16) {
#pragma unroll
        for (int i = 0; i < 8; ++i) red[w][lane * 8 + i] = acc[i];
    }
    __syncthreads();
    if (t < HID) {
        float v = red[0][t] + red[1][t] + red[2][t] + red[3][t];
        poolPart[((long)g * PSL + sl) * HID + t] = v;
    }
}

// ---------------- MLP head: sum slices, /n_g, @W2+b2 (hoisted layer-3), MLP ----------------
__global__ __launch_bounds__(128) void mlp_kernel(
    const float* __restrict__ poolPart, const int* __restrict__ batch,
    const float* __restrict__ W2f, const float* __restrict__ b2,
    const float* __restrict__ W1, const float* __restrict__ b1,
    const float* __restrict__ gamma, const float* __restrict__ beta,
    const float* __restrict__ mW2, const float* __restrict__ mb2, float* __restrict__ out)
{
    int g = blockIdx.x, t = threadIdx.x;
    __shared__ float pt[HID];
    __shared__ float p[HID];
    __shared__ float red[4];
    int lo = 0, hi = NN;
    while (lo < hi) { int m = (lo + hi) >> 1; if (batch[m] < g) lo = m + 1; else hi = m; }
    int ns = lo;
    lo = 0; hi = NN;
    while (lo < hi) { int m = (lo + hi) >> 1; if (batch[m] < g + 1) lo = m + 1; else hi = m; }
    float cnt = fmaxf((float)(lo - ns), 1.f);

    float v = 0.f;
#pragma unroll
    for (int s = 0; s < PSL; ++s) v += poolPart[((long)g * PSL + s) * HID + t];
    pt[t] = v / cnt;
    __syncthreads();
    float pv = b2[t];
    for (int k = 0; k < HID; ++k) pv += pt[k] * W2f[k * HID + t];
    p[t] = pv;
    __syncthreads();
    float acc = b1[t];
    for (int k = 0; k < HID; ++k) acc += p[k] * W1[k * HID + t];
    const float inv = 1.0f / sqrtf(1.0f + 1e-5f);
    acc = acc * (gamma[t] * inv) + beta[t];
    acc = fmaxf(acc, 0.f);
    float v0 = acc * mW2[t * 2 + 0];
    float v1 = acc * mW2[t * 2 + 1];
    for (int d = 32; d > 0; d >>= 1) { v0 += __shfl_down(v0, d); v1 += __shfl_down(v1, d); }
    int w = t >> 6, lane = t & 63;
    if (lane == 0) { red[w * 2] = v0; red[w * 2 + 1] = v1; }
    __syncthreads();
    if (t == 0) {
        out[g * 2 + 0] = red[0] + red[2] + mb2[0];
        out[g * 2 + 1] = red[1] + red[3] + mb2[1];
    }
}

extern "C" void kernel_launch(void* const* d_in, const int* in_sizes, int n_in,
                              void* d_out, int out_size, void* d_ws, size_t ws_size,
                              hipStream_t stream) {
    const int*   z        = (const int*)d_in[1];
    const int*   ei       = (const int*)d_in[2];
    const int*   batch    = (const int*)d_in[3];
    const int*   node_id  = (const int*)d_in[4];
    const float* z_emb    = (const float*)d_in[5];
    const float* node_emb = (const float*)d_in[6];
    const float* W0  = (const float*)d_in[7];
    const float* b0  = (const float*)d_in[8];
    const float* W1  = (const float*)d_in[9];
    const float* b1  = (const float*)d_in[10];
    const float* W2  = (const float*)d_in[11];
    const float* b2  = (const float*)d_in[12];
    const float* mW1 = (const float*)d_in[13];
    const float* mb1 = (const float*)d_in[14];
    const float* gam = (const float*)d_in[15];
    const float* bet = (const float*)d_in[16];
    const float* mW2 = (const float*)d_in[17];
    const float* mb2 = (const float*)d_in[18];
    float* out = (float*)d_out;

    const int* srcArr = ei;
    const int* dstArr = ei + NE;

    char* ws = (char*)d_ws;
    size_t o = 0;
    auto alloc = [&](size_t bytes) { char* p = ws + o; o += (bytes + 255) & ~(size_t)255; return p; };
    u16*   A      = (u16*)alloc((size_t)NN * HID * 2);
    u16*   B      = (u16*)alloc((size_t)NN * HID * 2);
    float* zW     = (float*)alloc((size_t)MAXZ * HID * 4);
    u16*   W0bt   = (u16*)alloc((size_t)HID * HID * 2);
    u16*   W1t    = (u16*)alloc((size_t)HID * HID * 2);
    int*   gcount = (int*)alloc((size_t)NBK * 4);
    u32*   pairs  = (u32*)alloc((size_t)NBK * CAP * 4);
    int*   off    = (int*)alloc((size_t)NN * 4);
    int*   endA   = (int*)alloc((size_t)NN * 4);
    int*   csr    = (int*)alloc((size_t)NBK * CAP * 4);
    float* poolP  = (float*)alloc((size_t)NG * PSL * HID * 4);
    (void)ws_size;

    // CSR by dst — fixed-capacity bucketed build (no count/scan prepass)
    hipMemsetAsync(gcount, 0, (size_t)NBK * 4, stream);
    pair_scatter_kernel<<<(NE + TILE_E - 1) / TILE_E, 256, 0, stream>>>(srcArr, dstArr, gcount, pairs);
    bucket_build_kernel<<<NBK, 256, 0, stream>>>(pairs, gcount, off, endA, csr);

    // weights (W0 bottom half + W1; W2 stays f32 and is applied post-pool)
    wt2_kernel<<<2 * HID, HID, 0, stream>>>(W0 + HID * HID, W1, W0bt, W1t);

    // zW = z_emb @ W0_top   (f32, tiny)
    gemm128_kernel<<<(MAXZ + 31) / 32, 256, 0, stream>>>(z_emb, W0, zW, MAXZ);

    const int GB = (NN + 63) / 64;
    // layer 0: B = bf16( node_emb[node_id] @ W0_bot + zW[z] )
    mfma_gemm_kernel<0><<<GB, 256, 0, stream>>>(node_emb, node_id, W0bt, zW, z, B, NN);
    aggregate_kernel<<<NN / 4, 256, 0, stream>>>(B, A, off, endA, csr, b0, NN, 1);
    // layer 1
    mfma_gemm_kernel<1><<<GB, 256, 0, stream>>>(A, nullptr, W1t, nullptr, nullptr, B, NN);
    aggregate_kernel<<<NN / 4, 256, 0, stream>>>(B, A, off, endA, csr, b1, NN, 1);
    // layer 2 fused with pooling (sliced, node-major): partials of pool(x2 + agg(x2))
    edgepool_kernel<<<NG * PSL, 256, 0, stream>>>(A, batch, off, endA, csr, poolP);
    mlp_kernel<<<NG, 128, 0, stream>>>(poolP, batch, W2, b2, mW1, mb1, gam, bet, mW2, mb2, out);
}